// Round 1
// 3265.853 us; speedup vs baseline: 1.5302x; 1.5302x over previous
//
#include <hip/hip_runtime.h>
#include <cstdint>
#include <cstddef>

typedef unsigned short u16;
typedef unsigned int u32;

#define DEV static __device__ __forceinline__

DEV u16 f2bf(float f) {
    u32 u = __builtin_bit_cast(u32, f);
    u += 0x7fffu + ((u >> 16) & 1u);
    return (u16)(u >> 16);
}
DEV float bf2f(u16 h) {
    u32 u = ((u32)h) << 16;
    return __builtin_bit_cast(float, u);
}
// bf16 pair unpack from a packed u32 (element 0 = low half, little-endian)
DEV float bflo(u32 w) { return __builtin_bit_cast(float, w << 16); }
DEV float bfhi(u32 w) { return __builtin_bit_cast(float, w & 0xffff0000u); }

#define LOG2E 1.4426950408889634f
#define NEGF (-1e30f)
#define NLOG2F (-0.41524101186092029f)  // -log2(10000)/32

// ---------------- rope table: tab[p*32+d] = {cos f, sin f}, f = p*10000^(-d/32) ----------------
// Bit-identical to the formula previously evaluated per-thread inside attn.
__global__ __launch_bounds__(256) void rope_table(float2* __restrict__ tab) {
    int idx = blockIdx.x * 256 + threadIdx.x;
    if (idx >= 384 * 32) return;
    int p = idx >> 5, d = idx & 31;
    float f = (float)p * exp2f(NLOG2F * (float)d);
    tab[idx] = make_float2(cosf(f), sinf(f));
}

// ---------------- tiled GEMM: C[M][N] = A[M][K] @ B[K][N](fp32) ----------------
// A fp32 (A_BF=false) or bf16 (A_BF=true); C fp32 (C_F32=true) or bf16.
// A-tile stored k-major in LDS so both fragments read as float4 (ds_read_b128).

template <bool A_BF, bool C_F32>
__global__ __launch_bounds__(256) void gemm_nn(const void* __restrict__ Ap, int lda,
                                               const float* __restrict__ B,
                                               void* __restrict__ Cp, int ldc,
                                               int N, int K) {
    __shared__ __align__(16) float As[16][68];  // [k][m], row stride 272B (16B mult)
    __shared__ __align__(16) float Bs[16][68];  // [k][n]
    const int tid = threadIdx.x;
    const int m0 = blockIdx.y * 64, n0 = blockIdx.x * 64;
    const int tx = tid & 15, ty = tid >> 4;

    float acc[4][4] = {};

    for (int k0 = 0; k0 < K; k0 += 16) {
        __syncthreads();
        {
            int r = tid >> 2;          // 0..63 : A row (m)
            int c = (tid & 3) * 4;     // 0,4,8,12 : A col (k)
            if (A_BF) {
                const u16* A = (const u16*)Ap;
                uint2 av = *(const uint2*)(A + (size_t)(m0 + r) * lda + k0 + c);
                As[c + 0][r] = bflo(av.x);
                As[c + 1][r] = bfhi(av.x);
                As[c + 2][r] = bflo(av.y);
                As[c + 3][r] = bfhi(av.y);
            } else {
                const float* A = (const float*)Ap;
                float4 av = *(const float4*)(A + (size_t)(m0 + r) * lda + k0 + c);
                As[c + 0][r] = av.x;
                As[c + 1][r] = av.y;
                As[c + 2][r] = av.z;
                As[c + 3][r] = av.w;
            }
            int r2 = tid >> 4;         // 0..15 : B row (k)
            int c2 = (tid & 15) * 4;   // 0..60 : B col (n)
            float4 bv = *(const float4*)(B + (size_t)(k0 + r2) * N + n0 + c2);
            *(float4*)&Bs[r2][c2] = bv;
        }
        __syncthreads();
#pragma unroll
        for (int kk = 0; kk < 16; ++kk) {
            float4 av = *(const float4*)&As[kk][ty * 4];
            float4 bv = *(const float4*)&Bs[kk][tx * 4];
            float a[4] = {av.x, av.y, av.z, av.w};
            float b[4] = {bv.x, bv.y, bv.z, bv.w};
#pragma unroll
            for (int i = 0; i < 4; ++i)
#pragma unroll
                for (int j = 0; j < 4; ++j) acc[i][j] += a[i] * b[j];
        }
    }

#pragma unroll
    for (int i = 0; i < 4; ++i) {
        size_t row = (size_t)(m0 + ty * 4 + i);
        if (C_F32) {
            float4 cv = make_float4(acc[i][0], acc[i][1], acc[i][2], acc[i][3]);
            *(float4*)((float*)Cp + row * ldc + n0 + tx * 4) = cv;
        } else {
            uint2 cv;
            cv.x = (u32)f2bf(acc[i][0]) | ((u32)f2bf(acc[i][1]) << 16);
            cv.y = (u32)f2bf(acc[i][2]) | ((u32)f2bf(acc[i][3]) << 16);
            *(uint2*)((u16*)Cp + row * ldc + n0 + tx * 4) = cv;
        }
    }
}

// ---------------- local attention, chunked-ILP, register-resident accumulators ----------------

__global__ __launch_bounds__(128, 1) void attn_simple(u16* __restrict__ qkv,
                                                      const float* __restrict__ q_scale,
                                                      const float* __restrict__ k_scale,
                                                      const float2* __restrict__ rt) {
    // Row strides are 16B multiples so rows can be read as float4/uint4.
    __shared__ __align__(16) float Ks[128][68];  // 34816 B
    __shared__ __align__(16) u16  Vs[128][72];   // 18432 B  (total 53248 -> 3 blocks/CU)

    const int win = blockIdx.x;
    const int bh  = blockIdx.y;
    const int bi  = bh >> 4, h = bh & 15;
    const int i   = threadIdx.x;

    float q[64], o[64];
    {
        size_t base = ((size_t)(bi * 8192 + win * 128 + i)) * 3072 + h * 64;
        const uint4* qp = (const uint4*)(qkv + base);
        float ss = 0.f;
#pragma unroll
        for (int dv = 0; dv < 8; ++dv) {
            uint4 rv = qp[dv];
            float f0 = bflo(rv.x), f1 = bfhi(rv.x), f2 = bflo(rv.y), f3 = bfhi(rv.y);
            float f4 = bflo(rv.z), f5 = bfhi(rv.z), f6 = bflo(rv.w), f7 = bfhi(rv.w);
            q[dv*8+0]=f0; q[dv*8+1]=f1; q[dv*8+2]=f2; q[dv*8+3]=f3;
            q[dv*8+4]=f4; q[dv*8+5]=f5; q[dv*8+6]=f6; q[dv*8+7]=f7;
            ss += f0*f0+f1*f1+f2*f2+f3*f3+f4*f4+f5*f5+f6*f6+f7*f7;
        }
        float inv = 8.0f / fmaxf(sqrtf(ss), 1e-12f);
        const float2* r = rt + (256 + i) * 32;
#pragma unroll
        for (int d = 0; d < 32; ++d) {
            float cs = r[d].x, sn = r[d].y;
            float x0 = q[d] * inv * q_scale[d];
            float x1 = q[d + 32] * inv * q_scale[d + 32];
            q[d]      = x0 * cs - x1 * sn;
            q[d + 32] = x1 * cs + x0 * sn;
        }
    }
#pragma unroll
    for (int d = 0; d < 64; ++d) o[d] = 0.f;
    float m = NEGF, l = 0.f;

    // One chunk = 8 keys: 8 independent dots (ILP), one rescale, batched exp.
    auto do_chunk = [&](int jc, int jlo, int jhi) {
        float s[8];
#pragma unroll
        for (int jj = 0; jj < 8; ++jj) {
            int j = jc + jj;
            const float4* kr = (const float4*)Ks[j];
            float a0 = 0.f, a1 = 0.f, a2 = 0.f, a3 = 0.f;
#pragma unroll
            for (int dq = 0; dq < 16; ++dq) {
                float4 kv = kr[dq];
                a0 += q[dq*4+0] * kv.x;
                a1 += q[dq*4+1] * kv.y;
                a2 += q[dq*4+2] * kv.z;
                a3 += q[dq*4+3] * kv.w;
            }
            float sv = (a0 + a1) + (a2 + a3);
            s[jj] = (j < jlo || j > jhi) ? NEGF : sv;
        }
        float cm = fmaxf(fmaxf(fmaxf(s[0], s[1]), fmaxf(s[2], s[3])),
                         fmaxf(fmaxf(s[4], s[5]), fmaxf(s[6], s[7])));
        float mn = fmaxf(m, cm);
        float al = exp2f((m - mn) * LOG2E);
        float p[8]; float ps = 0.f;
#pragma unroll
        for (int jj = 0; jj < 8; ++jj) { p[jj] = exp2f((s[jj] - mn) * LOG2E); ps += p[jj]; }
        l = l * al + ps;
        m = mn;
#pragma unroll
        for (int d = 0; d < 64; ++d) o[d] *= al;
#pragma unroll
        for (int jj = 0; jj < 8; ++jj) {
            float pj = p[jj];
            const uint4* vr = (const uint4*)Vs[jc + jj];
#pragma unroll
            for (int dv = 0; dv < 8; ++dv) {
                uint4 vv = vr[dv];
                o[dv*8+0] += pj * bflo(vv.x);
                o[dv*8+1] += pj * bfhi(vv.x);
                o[dv*8+2] += pj * bflo(vv.y);
                o[dv*8+3] += pj * bfhi(vv.y);
                o[dv*8+4] += pj * bflo(vv.z);
                o[dv*8+5] += pj * bfhi(vv.z);
                o[dv*8+6] += pj * bflo(vv.w);
                o[dv*8+7] += pj * bfhi(vv.w);
            }
        }
    };

    for (int c = 0; c < 3; ++c) {
        if (win == 0 && c == 0) continue;
        if (win == 63 && c == 2) continue;
        __syncthreads();
        {
            int t = (win - 1 + c) * 128 + i;
            size_t kb = ((size_t)(bi * 8192 + t)) * 3072 + 1024 + h * 64;
            const uint4* kp = (const uint4*)(qkv + kb);
            float x[64]; float ss = 0.f;
#pragma unroll
            for (int dv = 0; dv < 8; ++dv) {
                uint4 rv = kp[dv];
                float f0 = bflo(rv.x), f1 = bfhi(rv.x), f2 = bflo(rv.y), f3 = bfhi(rv.y);
                float f4 = bflo(rv.z), f5 = bfhi(rv.z), f6 = bflo(rv.w), f7 = bfhi(rv.w);
                x[dv*8+0]=f0; x[dv*8+1]=f1; x[dv*8+2]=f2; x[dv*8+3]=f3;
                x[dv*8+4]=f4; x[dv*8+5]=f5; x[dv*8+6]=f6; x[dv*8+7]=f7;
                ss += f0*f0+f1*f1+f2*f2+f3*f3+f4*f4+f5*f5+f6*f6+f7*f7;
            }
            float inv = 1.0f / fmaxf(sqrtf(ss), 1e-12f);
            const float2* r = rt + (c * 128 + i) * 32;
#pragma unroll
            for (int d = 0; d < 32; ++d) {
                float cs = r[d].x, sn = r[d].y;
                float x0 = x[d] * inv * k_scale[d];
                float x1 = x[d + 32] * inv * k_scale[d + 32];
                Ks[i][d]      = x0 * cs - x1 * sn;
                Ks[i][d + 32] = x1 * cs + x0 * sn;
            }
            const uint4* vp = (const uint4*)(qkv + kb + 1024);
            uint4* vd = (uint4*)Vs[i];
#pragma unroll
            for (int dv = 0; dv < 8; ++dv) vd[dv] = vp[dv];
        }
        __syncthreads();

        // Boundary windows iterate so that all active lanes share jc (LDS broadcast):
        // c==0: descend from the top; lanes drop out when below their own start.
        // c==2: ascend from 0; lanes drop out past their own end.
        if (c == 0) {
            const int lo = i & ~7;
#pragma unroll 1
            for (int jc = 120; jc >= lo; jc -= 8) do_chunk(jc, i, 127);
        } else if (c == 1) {
#pragma unroll 1
            for (int jc = 0; jc < 128; jc += 8) do_chunk(jc, 0, 127);
        } else {
#pragma unroll 1
            for (int jc = 0; jc <= i; jc += 8) do_chunk(jc, 0, i);
        }
    }

    size_t ob = ((size_t)(bi * 8192 + win * 128 + i)) * 3072 + h * 64;
    float linv = 1.0f / l;
    uint4* op = (uint4*)(qkv + ob);
#pragma unroll
    for (int dv = 0; dv < 8; ++dv) {
        uint4 cv;
        cv.x = (u32)f2bf(o[dv*8+0] * linv) | ((u32)f2bf(o[dv*8+1] * linv) << 16);
        cv.y = (u32)f2bf(o[dv*8+2] * linv) | ((u32)f2bf(o[dv*8+3] * linv) << 16);
        cv.z = (u32)f2bf(o[dv*8+4] * linv) | ((u32)f2bf(o[dv*8+5] * linv) << 16);
        cv.w = (u32)f2bf(o[dv*8+6] * linv) | ((u32)f2bf(o[dv*8+7] * linv) << 16);
        op[dv] = cv;
    }
}

// ---------------- host launcher ----------------

extern "C" void kernel_launch(void* const* d_in, const int* in_sizes, int n_in,
                              void* d_out, int out_size, void* d_ws, size_t ws_size,
                              hipStream_t stream) {
    // Inputs fp32; OUTPUT IS FP32 (harness reads d_out as float32).
    const float* x       = (const float*)d_in[0];  // [16384, 1024]
    const float* w_qkv   = (const float*)d_in[1];  // [1024, 3072]
    const float* w_out   = (const float*)d_in[2];  // [1024, 1024]
    const float* q_scale = (const float*)d_in[3];  // [64]
    const float* k_scale = (const float*)d_in[4];  // [64]
    float* outp = (float*)d_out;

    u16* qkv = (u16*)d_ws;            // 16384x3072 bf16 = 100,663,296 B
    float2* rt = (float2*)d_out;      // rope table (98,304 B) parked in d_out;
                                      // fully overwritten by the final GEMM.

    rope_table<<<dim3(48), 256, 0, stream>>>(rt);
    // qkv = x @ w_qkv   (A fp32, C bf16)
    gemm_nn<false, false><<<dim3(48, 256), 256, 0, stream>>>(x, 1024, w_qkv, qkv, 3072, 3072, 1024);
    // attention; O overwrites the q-slots of qkv (stride 3072)
    attn_simple<<<dim3(64, 32), 128, 0, stream>>>(qkv, q_scale, k_scale, rt);
    // out = O @ w_out   (A bf16 q-slots lda=3072, C fp32)
    gemm_nn<true, true><<<dim3(16, 256), 256, 0, stream>>>(qkv, 3072, w_out, outp, 1024, 1024, 1024);
}

// Round 2
// 2333.046 us; speedup vs baseline: 2.1420x; 1.3998x over previous
//
#include <hip/hip_runtime.h>
#include <cstdint>
#include <cstddef>

typedef unsigned short u16;
typedef unsigned int u32;

#define DEV static __device__ __forceinline__

DEV u16 f2bf(float f) {
    u32 u = __builtin_bit_cast(u32, f);
    u += 0x7fffu + ((u >> 16) & 1u);
    return (u16)(u >> 16);
}
DEV float bflo(u32 w) { return __builtin_bit_cast(float, w << 16); }
DEV float bfhi(u32 w) { return __builtin_bit_cast(float, w & 0xffff0000u); }
DEV u32 pk2(float a, float b) { return (u32)f2bf(a) | ((u32)f2bf(b) << 16); }

#define LOG2E 1.4426950408889634f
#define NEGF (-1e30f)
#define NLOG2F (-0.41524101186092029f)  // -log2(10000)/32

// butterfly sum over 4-lane groups via DPP quad_perm (pure VALU, no LDS pipe)
DEV float qsum4(float x) {
    float y = x + __builtin_bit_cast(float, __builtin_amdgcn_mov_dpp(
                      __builtin_bit_cast(int, x), 0xB1, 0xF, 0xF, true));  // xor 1
    float z = y + __builtin_bit_cast(float, __builtin_amdgcn_mov_dpp(
                      __builtin_bit_cast(int, y), 0x4E, 0xF, 0xF, true));  // xor 2
    return z;
}

// ---------------- rope table: tab[p*32+d] = {cos f, sin f}, f = p*10000^(-d/32) ----------------
__global__ __launch_bounds__(256) void rope_table(float2* __restrict__ tab) {
    int idx = blockIdx.x * 256 + threadIdx.x;
    if (idx >= 384 * 32) return;
    int p = idx >> 5, d = idx & 31;
    float f = (float)p * exp2f(NLOG2F * (float)d);
    tab[idx] = make_float2(cosf(f), sinf(f));
}

// ---------------- tiled GEMM: C[M][N] = A[M][K] @ B[K][N](fp32) ----------------
// 128x128 tile, 256 threads, 8x8 register tile per thread. A stored k-major.
// Bs column mapping adds 4 words per 32 (cmap) to break 4-way b-frag conflicts.

DEV int cmap(int c) { return c + ((c >> 5) << 2); }

template <bool A_BF, bool C_F32>
__global__ __launch_bounds__(256) void gemm_nn(const void* __restrict__ Ap, int lda,
                                               const float* __restrict__ B,
                                               void* __restrict__ Cp, int ldc,
                                               int N, int K) {
    __shared__ __align__(16) float As[16][132];   // [k][m]
    __shared__ __align__(16) float Bs[16][140];   // [k][cmap(n)]
    const int tid = threadIdx.x;
    const int m0 = blockIdx.y * 128, n0 = blockIdx.x * 128;
    const int tx = tid & 15, ty = tid >> 4;
    const int txm = cmap(tx * 8);

    const int ar = tid >> 1, ac = (tid & 1) * 8;   // A: 128 rows x 16 cols
    const int br = tid >> 4, bc = (tid & 15) * 8;  // B: 16 rows x 128 cols
    const int bcm = cmap(bc);

    float acc[8][8] = {};

    for (int k0 = 0; k0 < K; k0 += 16) {
        __syncthreads();
        if (A_BF) {
            const u16* A = (const u16*)Ap;
            uint4 av = *(const uint4*)(A + (size_t)(m0 + ar) * lda + k0 + ac);
            As[ac + 0][ar] = bflo(av.x); As[ac + 1][ar] = bfhi(av.x);
            As[ac + 2][ar] = bflo(av.y); As[ac + 3][ar] = bfhi(av.y);
            As[ac + 4][ar] = bflo(av.z); As[ac + 5][ar] = bfhi(av.z);
            As[ac + 6][ar] = bflo(av.w); As[ac + 7][ar] = bfhi(av.w);
        } else {
            const float* A = (const float*)Ap;
            const float4* ap4 = (const float4*)(A + (size_t)(m0 + ar) * lda + k0 + ac);
            float4 a0 = ap4[0], a1 = ap4[1];
            As[ac + 0][ar] = a0.x; As[ac + 1][ar] = a0.y;
            As[ac + 2][ar] = a0.z; As[ac + 3][ar] = a0.w;
            As[ac + 4][ar] = a1.x; As[ac + 5][ar] = a1.y;
            As[ac + 6][ar] = a1.z; As[ac + 7][ar] = a1.w;
        }
        {
            const float* bp = B + (size_t)(k0 + br) * N + n0 + bc;
            float4 b0 = *(const float4*)bp, b1 = *(const float4*)(bp + 4);
            *(float4*)&Bs[br][bcm]     = b0;
            *(float4*)&Bs[br][bcm + 4] = b1;
        }
        __syncthreads();
#pragma unroll
        for (int kk = 0; kk < 16; ++kk) {
            float4 a0 = *(const float4*)&As[kk][ty * 8];
            float4 a1 = *(const float4*)&As[kk][ty * 8 + 4];
            float4 b0 = *(const float4*)&Bs[kk][txm];
            float4 b1 = *(const float4*)&Bs[kk][txm + 4];
            float a[8] = {a0.x, a0.y, a0.z, a0.w, a1.x, a1.y, a1.z, a1.w};
            float b[8] = {b0.x, b0.y, b0.z, b0.w, b1.x, b1.y, b1.z, b1.w};
#pragma unroll
            for (int i = 0; i < 8; ++i)
#pragma unroll
                for (int j = 0; j < 8; ++j) acc[i][j] += a[i] * b[j];
        }
    }

#pragma unroll
    for (int i = 0; i < 8; ++i) {
        size_t row = (size_t)(m0 + ty * 8 + i);
        if (C_F32) {
            float* cp = (float*)Cp + row * ldc + n0 + tx * 8;
            *(float4*)cp       = make_float4(acc[i][0], acc[i][1], acc[i][2], acc[i][3]);
            *(float4*)(cp + 4) = make_float4(acc[i][4], acc[i][5], acc[i][6], acc[i][7]);
        } else {
            uint4 cv;
            cv.x = pk2(acc[i][0], acc[i][1]);
            cv.y = pk2(acc[i][2], acc[i][3]);
            cv.z = pk2(acc[i][4], acc[i][5]);
            cv.w = pk2(acc[i][6], acc[i][7]);
            *(uint4*)((u16*)Cp + row * ldc + n0 + tx * 8) = cv;
        }
    }
}

// ---------------- local attention: query-register-tiled (4q x 16d per thread) ----------------

DEV float bfx(const u32* kw, int d) {
    u32 w = kw[d >> 1];
    return (d & 1) ? bfhi(w) : bflo(w);
}

// load a 64-elem bf16 row, l2-normalize, scale, rope; write fp32 to dst[0..63]
DEV void rope_row(const u16* __restrict__ src, const float2* __restrict__ r,
                  const float* __restrict__ sc, float topmul, float* dst) {
    u32 kw[32];
    const uint4* p4 = (const uint4*)src;
#pragma unroll
    for (int t = 0; t < 8; ++t) {
        uint4 v = p4[t];
        kw[t * 4 + 0] = v.x; kw[t * 4 + 1] = v.y;
        kw[t * 4 + 2] = v.z; kw[t * 4 + 3] = v.w;
    }
    float ss = 0.f;
#pragma unroll
    for (int t = 0; t < 32; ++t) {
        float a = bflo(kw[t]), b = bfhi(kw[t]);
        ss += a * a + b * b;
    }
    float inv = topmul / fmaxf(sqrtf(ss), 1e-12f);
#pragma unroll
    for (int w = 0; w < 8; ++w) {
        float lo[4], hi[4];
#pragma unroll
        for (int t = 0; t < 4; ++t) {
            int d = w * 4 + t;  // < 32
            float2 cn = r[d];
            float x0 = bfx(kw, d) * inv * sc[d];
            float x1 = bfx(kw, d + 32) * inv * sc[d + 32];
            lo[t] = x0 * cn.x - x1 * cn.y;
            hi[t] = x1 * cn.x + x0 * cn.y;
        }
        *(float4*)(dst + w * 4)      = make_float4(lo[0], lo[1], lo[2], lo[3]);
        *(float4*)(dst + 32 + w * 4) = make_float4(hi[0], hi[1], hi[2], hi[3]);
    }
}

// MODE: 0 = valid iff j >= qi (left block), 1 = all valid, 2 = valid iff j <= qi (right block)
template <int MODE>
DEV void do_chunk(int jc, int qb4, int dg,
                  const float (&q)[4][16], float (&o)[4][16],
                  float (&m)[4], float (&l)[4],
                  const float (*Ksp)[68], const u16 (*Vsp)[72]) {
    float s[4][8];
#pragma unroll
    for (int jj = 0; jj < 8; ++jj) {
        const float4* kr = (const float4*)&Ksp[jc + jj][dg * 16];
        float4 k0 = kr[0], k1 = kr[1], k2 = kr[2], k3 = kr[3];
#pragma unroll
        for (int u = 0; u < 4; ++u) {
            float a0 = q[u][0] * k0.x + q[u][4] * k1.x;
            float a1 = q[u][1] * k0.y + q[u][5] * k1.y;
            float a2 = q[u][2] * k0.z + q[u][6] * k1.z;
            float a3 = q[u][3] * k0.w + q[u][7] * k1.w;
            a0 += q[u][8] * k2.x;  a1 += q[u][9] * k2.y;
            a2 += q[u][10] * k2.z; a3 += q[u][11] * k2.w;
            a0 += q[u][12] * k3.x; a1 += q[u][13] * k3.y;
            a2 += q[u][14] * k3.z; a3 += q[u][15] * k3.w;
            s[u][jj] = (a0 + a1) + (a2 + a3);
        }
    }
    // reduce partial dots across the 4-lane d-groups (bitwise-identical in all 4 lanes)
#pragma unroll
    for (int u = 0; u < 4; ++u)
#pragma unroll
        for (int jj = 0; jj < 8; ++jj) s[u][jj] = qsum4(s[u][jj]);

#pragma unroll
    for (int u = 0; u < 4; ++u) {
        const int qi = qb4 + u;
        float sv[8];
#pragma unroll
        for (int jj = 0; jj < 8; ++jj) {
            int j = jc + jj;
            bool ok = (MODE == 1) || (MODE == 0 ? (j >= qi) : (j <= qi));
            sv[jj] = ok ? s[u][jj] : NEGF;
        }
        float cm = fmaxf(fmaxf(fmaxf(sv[0], sv[1]), fmaxf(sv[2], sv[3])),
                         fmaxf(fmaxf(sv[4], sv[5]), fmaxf(sv[6], sv[7])));
        float mn = fmaxf(m[u], cm);
        float al = exp2f((m[u] - mn) * LOG2E);
        float ps = 0.f;
#pragma unroll
        for (int jj = 0; jj < 8; ++jj) {
            int j = jc + jj;
            bool ok = (MODE == 1) || (MODE == 0 ? (j >= qi) : (j <= qi));
            float p = ok ? exp2f((sv[jj] - mn) * LOG2E) : 0.f;  // explicit 0: NEGF-NEGF trap
            s[u][jj] = p;
            ps += p;
        }
        l[u] = l[u] * al + ps;
        m[u] = mn;
#pragma unroll
        for (int d = 0; d < 16; ++d) o[u][d] *= al;
    }

#pragma unroll
    for (int jj = 0; jj < 8; ++jj) {
        const uint4* vr = (const uint4*)&Vsp[jc + jj][dg * 16];
        uint4 v0 = vr[0], v1 = vr[1];
        float vf[16] = {bflo(v0.x), bfhi(v0.x), bflo(v0.y), bfhi(v0.y),
                        bflo(v0.z), bfhi(v0.z), bflo(v0.w), bfhi(v0.w),
                        bflo(v1.x), bfhi(v1.x), bflo(v1.y), bfhi(v1.y),
                        bflo(v1.z), bfhi(v1.z), bflo(v1.w), bfhi(v1.w)};
#pragma unroll
        for (int u = 0; u < 4; ++u) {
            float pj = s[u][jj];
#pragma unroll
            for (int d = 0; d < 16; ++d) o[u][d] += pj * vf[d];
        }
    }
}

__global__ __launch_bounds__(128, 2) void attn_reg(u16* __restrict__ qkv,
                                                   const float* __restrict__ q_scale,
                                                   const float* __restrict__ k_scale,
                                                   const float2* __restrict__ rt) {
    __shared__ __align__(16) float Ks[128][68];  // 34816 B (also Q staging)
    __shared__ __align__(16) u16  Vs[128][72];   // 18432 B -> total 53248, 3 blk/CU

    const int win = blockIdx.x;
    const int bh  = blockIdx.y;
    const int bi  = bh >> 4, h = bh & 15;
    const int tid = threadIdx.x;
    const int dg  = tid & 3;          // d-slice: dg*16 .. dg*16+15
    const int qb  = tid >> 2;         // query group: queries qb*4 .. qb*4+3
    const int qb4 = qb * 4;
    const int wv  = tid >> 6;         // wave id (wave0: queries 0..63, wave1: 64..127)

    // ---- stage Q (roped, x8, q_scale) through Ks, then read register fragments ----
    {
        const u16* src = qkv + ((size_t)(bi * 8192 + win * 128 + tid)) * 3072 + h * 64;
        rope_row(src, rt + (256 + tid) * 32, q_scale, 8.0f, &Ks[tid][0]);
    }
    __syncthreads();
    float q[4][16];
#pragma unroll
    for (int u = 0; u < 4; ++u) {
        const float4* qr = (const float4*)&Ks[qb4 + u][dg * 16];
#pragma unroll
        for (int w = 0; w < 4; ++w) {
            float4 f = qr[w];
            q[u][w * 4 + 0] = f.x; q[u][w * 4 + 1] = f.y;
            q[u][w * 4 + 2] = f.z; q[u][w * 4 + 3] = f.w;
        }
    }
    float o[4][16];
#pragma unroll
    for (int u = 0; u < 4; ++u)
#pragma unroll
        for (int d = 0; d < 16; ++d) o[u][d] = 0.f;
    float m[4] = {NEGF, NEGF, NEGF, NEGF};
    float l[4] = {0.f, 0.f, 0.f, 0.f};

    for (int c = 0; c < 3; ++c) {
        if (win == 0 && c == 0) continue;
        if (win == 63 && c == 2) continue;
        __syncthreads();
        {
            int t = (win - 1 + c) * 128 + tid;
            const u16* src = qkv + ((size_t)(bi * 8192 + t)) * 3072 + 1024 + h * 64;
            rope_row(src, rt + (c * 128 + tid) * 32, k_scale, 1.0f, &Ks[tid][0]);
            const uint4* vp = (const uint4*)(src + 1024);
            uint4* vd = (uint4*)&Vs[tid][0];
#pragma unroll
            for (int t2 = 0; t2 < 8; ++t2) vd[t2] = vp[t2];
        }
        __syncthreads();

        if (c == 0) {
#pragma unroll 1
            for (int ci = wv * 8; ci < 16; ++ci)
                do_chunk<0>(ci * 8, qb4, dg, q, o, m, l, Ks, Vs);
        } else if (c == 1) {
#pragma unroll 1
            for (int ci = 0; ci < 16; ++ci)
                do_chunk<1>(ci * 8, qb4, dg, q, o, m, l, Ks, Vs);
        } else {
            const int ce = wv ? 16 : 8;
#pragma unroll 1
            for (int ci = 0; ci < ce; ++ci)
                do_chunk<2>(ci * 8, qb4, dg, q, o, m, l, Ks, Vs);
        }
    }

    // ---- epilogue: O back into the q-slots ----
#pragma unroll
    for (int u = 0; u < 4; ++u) {
        float linv = 1.0f / l[u];
        u16* orow = qkv + ((size_t)(bi * 8192 + win * 128 + qb4 + u)) * 3072 + h * 64 + dg * 16;
        uint4 c0, c1;
        c0.x = pk2(o[u][0] * linv,  o[u][1] * linv);
        c0.y = pk2(o[u][2] * linv,  o[u][3] * linv);
        c0.z = pk2(o[u][4] * linv,  o[u][5] * linv);
        c0.w = pk2(o[u][6] * linv,  o[u][7] * linv);
        c1.x = pk2(o[u][8] * linv,  o[u][9] * linv);
        c1.y = pk2(o[u][10] * linv, o[u][11] * linv);
        c1.z = pk2(o[u][12] * linv, o[u][13] * linv);
        c1.w = pk2(o[u][14] * linv, o[u][15] * linv);
        *(uint4*)orow       = c0;
        *(uint4*)(orow + 8) = c1;
    }
}

// ---------------- host launcher ----------------

extern "C" void kernel_launch(void* const* d_in, const int* in_sizes, int n_in,
                              void* d_out, int out_size, void* d_ws, size_t ws_size,
                              hipStream_t stream) {
    // Inputs fp32; OUTPUT IS FP32 (harness reads d_out as float32).
    const float* x       = (const float*)d_in[0];  // [16384, 1024]
    const float* w_qkv   = (const float*)d_in[1];  // [1024, 3072]
    const float* w_out   = (const float*)d_in[2];  // [1024, 1024]
    const float* q_scale = (const float*)d_in[3];  // [64]
    const float* k_scale = (const float*)d_in[4];  // [64]
    float* outp = (float*)d_out;

    u16* qkv = (u16*)d_ws;        // 16384x3072 bf16 = 100,663,296 B
    float2* rt = (float2*)d_out;  // rope table (96 KB) parked in d_out;
                                  // fully overwritten by the final GEMM.

    rope_table<<<dim3(48), 256, 0, stream>>>(rt);
    // qkv = x @ w_qkv   (A fp32, C bf16)
    gemm_nn<false, false><<<dim3(24, 128), 256, 0, stream>>>(x, 1024, w_qkv, qkv, 3072, 3072, 1024);
    // attention; O overwrites the q-slots of qkv (stride 3072)
    attn_reg<<<dim3(64, 32), 128, 0, stream>>>(qkv, q_scale, k_scale, rt);
    // out = O @ w_out   (A bf16 q-slots lda=3072, C fp32)
    gemm_nn<true, true><<<dim3(8, 128), 256, 0, stream>>>(qkv, 3072, w_out, outp, 1024, 1024, 1024);
}

// Round 4
// 1360.362 us; speedup vs baseline: 3.6736x; 1.7150x over previous
//
#include <hip/hip_runtime.h>
#include <cstdint>
#include <cstddef>

typedef unsigned short u16;
typedef unsigned int u32;
typedef _Float16 f16;
typedef __attribute__((ext_vector_type(8))) _Float16 f16x8;
typedef __attribute__((ext_vector_type(4))) float f32x4;

#define DEV static __device__ __forceinline__

DEV u16 f2h(float f) { return __builtin_bit_cast(u16, (_Float16)f); }
DEV float h2f(u16 h) { return (float)__builtin_bit_cast(_Float16, h); }
DEV float hlo(u32 w) { return (float)__builtin_bit_cast(_Float16, (u16)(w & 0xffffu)); }
DEV float hhi(u32 w) { return (float)__builtin_bit_cast(_Float16, (u16)(w >> 16)); }
DEV u32 pk2h(float a, float b) { return (u32)f2h(a) | ((u32)f2h(b) << 16); }

#define LOG2E 1.4426950408889634f
#define NEGF (-1e30f)
#define NLOG2F (-0.41524101186092029f)  // -log2(10000)/32

// butterfly sum over 4-lane groups via DPP quad_perm (pure VALU, no LDS pipe)
DEV float qsum4(float x) {
    float y = x + __builtin_bit_cast(float, __builtin_amdgcn_mov_dpp(
                      __builtin_bit_cast(int, x), 0xB1, 0xF, 0xF, true));  // xor 1
    float z = y + __builtin_bit_cast(float, __builtin_amdgcn_mov_dpp(
                      __builtin_bit_cast(int, y), 0x4E, 0xF, 0xF, true));  // xor 2
    return z;
}

// ---------------- rope table: tab[p*32+d] = {cos f, sin f}, f = p*10000^(-d/32) ----------------
__global__ __launch_bounds__(256) void rope_table(float2* __restrict__ tab) {
    int idx = blockIdx.x * 256 + threadIdx.x;
    if (idx >= 384 * 32) return;
    int p = idx >> 5, d = idx & 31;
    float f = (float)p * exp2f(NLOG2F * (float)d);
    tab[idx] = make_float2(cosf(f), sinf(f));
}

// ---------------- fp32 -> fp16 convert (n8 groups of 8) ----------------
__global__ __launch_bounds__(256) void cvt_f32_f16(const float* __restrict__ in,
                                                   u16* __restrict__ out, int n8) {
    int idx = blockIdx.x * 256 + threadIdx.x;
    int stride = gridDim.x * 256;
    for (int i = idx; i < n8; i += stride) {
        const float4* p = (const float4*)(in + (size_t)i * 8);
        float4 v0 = p[0], v1 = p[1];
        uint4 o;
        o.x = pk2h(v0.x, v0.y); o.y = pk2h(v0.z, v0.w);
        o.z = pk2h(v1.x, v1.y); o.w = pk2h(v1.z, v1.w);
        *(uint4*)(out + (size_t)i * 8) = o;
    }
}

// ---------------- fp32 [R][C] -> fp16 transposed [C][R] ----------------
__global__ __launch_bounds__(256) void transpose_cvt(const float* __restrict__ in,
                                                     u16* __restrict__ out, int R, int C) {
    __shared__ u16 t[32][33];
    int rb = blockIdx.y * 32, cb = blockIdx.x * 32;
    int x = threadIdx.x & 31, y = threadIdx.x >> 5;  // y: 0..7
#pragma unroll
    for (int yy = 0; yy < 4; ++yy) {
        int rr = y + yy * 8;
        t[x][rr] = f2h(in[(size_t)(rb + rr) * C + cb + x]);
    }
    __syncthreads();
#pragma unroll
    for (int yy = 0; yy < 4; ++yy) {
        int rr = y + yy * 8;
        out[(size_t)(cb + rr) * R + rb + x] = t[rr][x];
    }
}

// ---------------- MFMA fp16 GEMM (m97 structure): C[M][N] = A[M][K] @ BT[N][K]^T ----------------
// 128x128 tile, 4 waves (2x2 quadrants of 64x64), BK=64, 16x16x32 f16 MFMA.
// LDS tiles [128 rows][64 k] fp16, row stride 128B, st_16x32 XOR swizzle:
//   16B-slot s of row r sits at byte r*128 + (s ^ (r&7))*16.
// global_load_lds writes LINEAR dest (rule #21): the global SOURCE address is
// inverse-swizzled so the swizzled ds_read recovers k = slot*8 correctly.

DEV void gload16(const void* g, void* l) {
    __builtin_amdgcn_global_load_lds(
        (const __attribute__((address_space(1))) unsigned int*)g,
        (__attribute__((address_space(3))) unsigned int*)l, 16, 0, 0);
}

__global__ __launch_bounds__(256) void gemm_mfma(const u16* __restrict__ A, int lda,
                                                 const u16* __restrict__ BT, int ldb,
                                                 u16* __restrict__ Cp, int ldc,
                                                 int K) {
    __shared__ __align__(16) u16 As[128 * 64];
    __shared__ __align__(16) u16 Bs[128 * 64];
    const int tid = threadIdx.x;
    const int w = tid >> 6, l = tid & 63;
    const int m0 = blockIdx.y * 128, n0 = blockIdx.x * 128;
    const int wr = (w >> 1) * 64, wc = (w & 1) * 64;  // wave quadrant origin
    const int r = l & 15, g = l >> 4;

    f32x4 acc[4][4] = {};

    for (int k0 = 0; k0 < K; k0 += 64) {
        __syncthreads();
#pragma unroll
        for (int i = 0; i < 4; ++i) {
            // chunk covers LDS bytes [chunk*1024, +1024): rows chunk*8..chunk*8+7
            int chunk = i * 4 + w;
            int row = chunk * 8 + (l >> 3);
            int ksrc = ((l & 7) ^ (row & 7)) * 8;  // inverse-swizzled source slot
            gload16(A + (size_t)(m0 + row) * lda + k0 + ksrc, &As[chunk * 512]);
            gload16(BT + (size_t)(n0 + row) * ldb + k0 + ksrc, &Bs[chunk * 512]);
        }
        __syncthreads();
#pragma unroll
        for (int kk = 0; kk < 2; ++kk) {
            f16x8 a[4], b[4];
#pragma unroll
            for (int mi = 0; mi < 4; ++mi) {
                int row = wr + mi * 16 + r;
                int byte = row * 128 + (((kk * 4 + g) ^ (row & 7)) << 4);
                a[mi] = *(const f16x8*)((const char*)As + byte);
            }
#pragma unroll
            for (int ni = 0; ni < 4; ++ni) {
                int row = wc + ni * 16 + r;
                int byte = row * 128 + (((kk * 4 + g) ^ (row & 7)) << 4);
                b[ni] = *(const f16x8*)((const char*)Bs + byte);
            }
#pragma unroll
            for (int mi = 0; mi < 4; ++mi)
#pragma unroll
                for (int ni = 0; ni < 4; ++ni)
                    acc[mi][ni] = __builtin_amdgcn_mfma_f32_16x16x32_f16(
                        a[mi], b[ni], acc[mi][ni], 0, 0, 0);
        }
    }

    // C/D layout (m89, dtype-independent): col = lane&15, row = (lane>>4)*4 + reg
#pragma unroll
    for (int mi = 0; mi < 4; ++mi)
#pragma unroll
        for (int ni = 0; ni < 4; ++ni) {
            int row0 = m0 + wr + mi * 16 + g * 4;
            int col  = n0 + wc + ni * 16 + r;
#pragma unroll
            for (int rr = 0; rr < 4; ++rr)
                Cp[(size_t)(row0 + rr) * ldc + col] = f2h(acc[mi][ni][rr]);
        }
}

// ---------------- fp32-VALU GEMM (proven in R2): C[M][N] = A[M][K](f16) @ B[K][N](f32) ----------------
// 128x128 tile, 256 threads, 8x8 register tile per thread. A stored k-major.
// Bs column mapping adds 4 words per 32 (cmap) to break 4-way b-frag conflicts.

DEV int cmap(int c) { return c + ((c >> 5) << 2); }

__global__ __launch_bounds__(256) void gemm_nn_f32(const u16* __restrict__ A, int lda,
                                                   const float* __restrict__ B,
                                                   float* __restrict__ Cp, int ldc,
                                                   int N, int K) {
    __shared__ __align__(16) float As[16][132];   // [k][m]
    __shared__ __align__(16) float Bs[16][140];   // [k][cmap(n)]
    const int tid = threadIdx.x;
    const int m0 = blockIdx.y * 128, n0 = blockIdx.x * 128;
    const int tx = tid & 15, ty = tid >> 4;
    const int txm = cmap(tx * 8);

    const int ar = tid >> 1, ac = (tid & 1) * 8;   // A: 128 rows x 16 cols
    const int br = tid >> 4, bc = (tid & 15) * 8;  // B: 16 rows x 128 cols
    const int bcm = cmap(bc);

    float acc[8][8] = {};

    for (int k0 = 0; k0 < K; k0 += 16) {
        __syncthreads();
        {
            uint4 av = *(const uint4*)(A + (size_t)(m0 + ar) * lda + k0 + ac);
            As[ac + 0][ar] = hlo(av.x); As[ac + 1][ar] = hhi(av.x);
            As[ac + 2][ar] = hlo(av.y); As[ac + 3][ar] = hhi(av.y);
            As[ac + 4][ar] = hlo(av.z); As[ac + 5][ar] = hhi(av.z);
            As[ac + 6][ar] = hlo(av.w); As[ac + 7][ar] = hhi(av.w);
        }
        {
            const float* bp = B + (size_t)(k0 + br) * N + n0 + bc;
            float4 b0 = *(const float4*)bp, b1 = *(const float4*)(bp + 4);
            *(float4*)&Bs[br][bcm]     = b0;
            *(float4*)&Bs[br][bcm + 4] = b1;
        }
        __syncthreads();
#pragma unroll
        for (int kk = 0; kk < 16; ++kk) {
            float4 a0 = *(const float4*)&As[kk][ty * 8];
            float4 a1 = *(const float4*)&As[kk][ty * 8 + 4];
            float4 b0 = *(const float4*)&Bs[kk][txm];
            float4 b1 = *(const float4*)&Bs[kk][txm + 4];
            float a[8] = {a0.x, a0.y, a0.z, a0.w, a1.x, a1.y, a1.z, a1.w};
            float b[8] = {b0.x, b0.y, b0.z, b0.w, b1.x, b1.y, b1.z, b1.w};
#pragma unroll
            for (int i = 0; i < 8; ++i)
#pragma unroll
                for (int j = 0; j < 8; ++j) acc[i][j] += a[i] * b[j];
        }
    }

#pragma unroll
    for (int i = 0; i < 8; ++i) {
        size_t row = (size_t)(m0 + ty * 8 + i);
        float* cp = Cp + row * ldc + n0 + tx * 8;
        *(float4*)cp       = make_float4(acc[i][0], acc[i][1], acc[i][2], acc[i][3]);
        *(float4*)(cp + 4) = make_float4(acc[i][4], acc[i][5], acc[i][6], acc[i][7]);
    }
}

// ---------------- local attention: query-register-tiled (4q x 16d per thread), fp16 qkv ----------------

DEV float hx(const u32* kw, int d) {
    u32 w = kw[d >> 1];
    return (d & 1) ? hhi(w) : hlo(w);
}

// load a 64-elem fp16 row, l2-normalize, scale, rope; write fp32 to dst[0..63]
DEV void rope_row(const u16* __restrict__ src, const float2* __restrict__ r,
                  const float* __restrict__ sc, float topmul, float* dst) {
    u32 kw[32];
    const uint4* p4 = (const uint4*)src;
#pragma unroll
    for (int t = 0; t < 8; ++t) {
        uint4 v = p4[t];
        kw[t * 4 + 0] = v.x; kw[t * 4 + 1] = v.y;
        kw[t * 4 + 2] = v.z; kw[t * 4 + 3] = v.w;
    }
    float ss = 0.f;
#pragma unroll
    for (int t = 0; t < 32; ++t) {
        float a = hlo(kw[t]), b = hhi(kw[t]);
        ss += a * a + b * b;
    }
    float inv = topmul / fmaxf(sqrtf(ss), 1e-12f);
#pragma unroll
    for (int w = 0; w < 8; ++w) {
        float lo[4], hi[4];
#pragma unroll
        for (int t = 0; t < 4; ++t) {
            int d = w * 4 + t;  // < 32
            float2 cn = r[d];
            float x0 = hx(kw, d) * inv * sc[d];
            float x1 = hx(kw, d + 32) * inv * sc[d + 32];
            lo[t] = x0 * cn.x - x1 * cn.y;
            hi[t] = x1 * cn.x + x0 * cn.y;
        }
        *(float4*)(dst + w * 4)      = make_float4(lo[0], lo[1], lo[2], lo[3]);
        *(float4*)(dst + 32 + w * 4) = make_float4(hi[0], hi[1], hi[2], hi[3]);
    }
}

// MODE: 0 = valid iff j >= qi (left block), 1 = all valid, 2 = valid iff j <= qi (right block)
template <int MODE>
DEV void do_chunk(int jc, int qb4, int dg,
                  const float (&q)[4][16], float (&o)[4][16],
                  float (&m)[4], float (&l)[4],
                  const float (*Ksp)[68], const u16 (*Vsp)[72]) {
    float s[4][8];
#pragma unroll
    for (int jj = 0; jj < 8; ++jj) {
        const float4* kr = (const float4*)&Ksp[jc + jj][dg * 16];
        float4 k0 = kr[0], k1 = kr[1], k2 = kr[2], k3 = kr[3];
#pragma unroll
        for (int u = 0; u < 4; ++u) {
            float a0 = q[u][0] * k0.x + q[u][4] * k1.x;
            float a1 = q[u][1] * k0.y + q[u][5] * k1.y;
            float a2 = q[u][2] * k0.z + q[u][6] * k1.z;
            float a3 = q[u][3] * k0.w + q[u][7] * k1.w;
            a0 += q[u][8] * k2.x;  a1 += q[u][9] * k2.y;
            a2 += q[u][10] * k2.z; a3 += q[u][11] * k2.w;
            a0 += q[u][12] * k3.x; a1 += q[u][13] * k3.y;
            a2 += q[u][14] * k3.z; a3 += q[u][15] * k3.w;
            s[u][jj] = (a0 + a1) + (a2 + a3);
        }
    }
    // reduce partial dots across the 4-lane d-groups (bitwise-identical in all 4 lanes)
#pragma unroll
    for (int u = 0; u < 4; ++u)
#pragma unroll
        for (int jj = 0; jj < 8; ++jj) s[u][jj] = qsum4(s[u][jj]);

#pragma unroll
    for (int u = 0; u < 4; ++u) {
        const int qi = qb4 + u;
        float sv[8];
#pragma unroll
        for (int jj = 0; jj < 8; ++jj) {
            int j = jc + jj;
            bool ok = (MODE == 1) || (MODE == 0 ? (j >= qi) : (j <= qi));
            sv[jj] = ok ? s[u][jj] : NEGF;
        }
        float cm = fmaxf(fmaxf(fmaxf(sv[0], sv[1]), fmaxf(sv[2], sv[3])),
                         fmaxf(fmaxf(sv[4], sv[5]), fmaxf(sv[6], sv[7])));
        float mn = fmaxf(m[u], cm);
        float al = exp2f((m[u] - mn) * LOG2E);
        float ps = 0.f;
#pragma unroll
        for (int jj = 0; jj < 8; ++jj) {
            int j = jc + jj;
            bool ok = (MODE == 1) || (MODE == 0 ? (j >= qi) : (j <= qi));
            float p = ok ? exp2f((sv[jj] - mn) * LOG2E) : 0.f;  // explicit 0: NEGF-NEGF trap
            s[u][jj] = p;
            ps += p;
        }
        l[u] = l[u] * al + ps;
        m[u] = mn;
#pragma unroll
        for (int d = 0; d < 16; ++d) o[u][d] *= al;
    }

#pragma unroll
    for (int jj = 0; jj < 8; ++jj) {
        const uint4* vr = (const uint4*)&Vsp[jc + jj][dg * 16];
        uint4 v0 = vr[0], v1 = vr[1];
        float vf[16] = {hlo(v0.x), hhi(v0.x), hlo(v0.y), hhi(v0.y),
                        hlo(v0.z), hhi(v0.z), hlo(v0.w), hhi(v0.w),
                        hlo(v1.x), hhi(v1.x), hlo(v1.y), hhi(v1.y),
                        hlo(v1.z), hhi(v1.z), hlo(v1.w), hhi(v1.w)};
#pragma unroll
        for (int u = 0; u < 4; ++u) {
            float pj = s[u][jj];
#pragma unroll
            for (int d = 0; d < 16; ++d) o[u][d] += pj * vf[d];
        }
    }
}

__global__ __launch_bounds__(128, 2) void attn_reg(u16* __restrict__ qkv,
                                                   const float* __restrict__ q_scale,
                                                   const float* __restrict__ k_scale,
                                                   const float2* __restrict__ rt) {
    __shared__ __align__(16) float Ks[128][68];  // 34816 B (also Q staging)
    __shared__ __align__(16) u16  Vs[128][72];   // 18432 B -> total 53248, 3 blk/CU

    const int win = blockIdx.x;
    const int bh  = blockIdx.y;
    const int bi  = bh >> 4, h = bh & 15;
    const int tid = threadIdx.x;
    const int dg  = tid & 3;          // d-slice: dg*16 .. dg*16+15
    const int qb  = tid >> 2;         // query group: queries qb*4 .. qb*4+3
    const int qb4 = qb * 4;
    const int wv  = tid >> 6;         // wave id (wave0: queries 0..63, wave1: 64..127)

    // ---- stage Q (roped, x8, q_scale) through Ks, then read register fragments ----
    {
        const u16* src = qkv + ((size_t)(bi * 8192 + win * 128 + tid)) * 3072 + h * 64;
        rope_row(src, rt + (256 + tid) * 32, q_scale, 8.0f, &Ks[tid][0]);
    }
    __syncthreads();
    float q[4][16];
#pragma unroll
    for (int u = 0; u < 4; ++u) {
        const float4* qr = (const float4*)&Ks[qb4 + u][dg * 16];
#pragma unroll
        for (int w = 0; w < 4; ++w) {
            float4 f = qr[w];
            q[u][w * 4 + 0] = f.x; q[u][w * 4 + 1] = f.y;
            q[u][w * 4 + 2] = f.z; q[u][w * 4 + 3] = f.w;
        }
    }
    float o[4][16];
#pragma unroll
    for (int u = 0; u < 4; ++u)
#pragma unroll
        for (int d = 0; d < 16; ++d) o[u][d] = 0.f;
    float m[4] = {NEGF, NEGF, NEGF, NEGF};
    float l[4] = {0.f, 0.f, 0.f, 0.f};

    for (int c = 0; c < 3; ++c) {
        if (win == 0 && c == 0) continue;
        if (win == 63 && c == 2) continue;
        __syncthreads();
        {
            int t = (win - 1 + c) * 128 + tid;
            const u16* src = qkv + ((size_t)(bi * 8192 + t)) * 3072 + 1024 + h * 64;
            rope_row(src, rt + (c * 128 + tid) * 32, k_scale, 1.0f, &Ks[tid][0]);
            const uint4* vp = (const uint4*)(src + 1024);
            uint4* vd = (uint4*)&Vs[tid][0];
#pragma unroll
            for (int t2 = 0; t2 < 8; ++t2) vd[t2] = vp[t2];
        }
        __syncthreads();

        if (c == 0) {
#pragma unroll 1
            for (int ci = wv * 8; ci < 16; ++ci)
                do_chunk<0>(ci * 8, qb4, dg, q, o, m, l, Ks, Vs);
        } else if (c == 1) {
#pragma unroll 1
            for (int ci = 0; ci < 16; ++ci)
                do_chunk<1>(ci * 8, qb4, dg, q, o, m, l, Ks, Vs);
        } else {
            const int ce = wv ? 16 : 8;
#pragma unroll 1
            for (int ci = 0; ci < ce; ++ci)
                do_chunk<2>(ci * 8, qb4, dg, q, o, m, l, Ks, Vs);
        }
    }

    // ---- epilogue: O back into the q-slots (fp16) ----
#pragma unroll
    for (int u = 0; u < 4; ++u) {
        float linv = 1.0f / l[u];
        u16* orow = qkv + ((size_t)(bi * 8192 + win * 128 + qb4 + u)) * 3072 + h * 64 + dg * 16;
        uint4 c0, c1;
        c0.x = pk2h(o[u][0] * linv,  o[u][1] * linv);
        c0.y = pk2h(o[u][2] * linv,  o[u][3] * linv);
        c0.z = pk2h(o[u][4] * linv,  o[u][5] * linv);
        c0.w = pk2h(o[u][6] * linv,  o[u][7] * linv);
        c1.x = pk2h(o[u][8] * linv,  o[u][9] * linv);
        c1.y = pk2h(o[u][10] * linv, o[u][11] * linv);
        c1.z = pk2h(o[u][12] * linv, o[u][13] * linv);
        c1.w = pk2h(o[u][14] * linv, o[u][15] * linv);
        *(uint4*)orow       = c0;
        *(uint4*)(orow + 8) = c1;
    }
}

// ---------------- host launcher ----------------

extern "C" void kernel_launch(void* const* d_in, const int* in_sizes, int n_in,
                              void* d_out, int out_size, void* d_ws, size_t ws_size,
                              hipStream_t stream) {
    // Inputs fp32; OUTPUT IS FP32 (harness reads d_out as float32).
    const float* x       = (const float*)d_in[0];  // [16384, 1024]
    const float* w_qkv   = (const float*)d_in[1];  // [1024, 3072]
    const float* w_out   = (const float*)d_in[2];  // [1024, 1024]
    const float* q_scale = (const float*)d_in[3];  // [64]
    const float* k_scale = (const float*)d_in[4];  // [64]
    float* outp = (float*)d_out;

    // ws: qkv fp16 ONLY = 100,663,296 B (the extent validated by earlier rounds —
    // R3 placed extra buffers past this and the container died; suspected overrun).
    u16* qkv = (u16*)d_ws;
    // d_out staging, all consumed before the final GEMM writes d_out:
    //   xh  [0, 33,554,432)         16384x1024 fp16  (read by gemm_mfma)
    //   wqT [33,554,432, 39,845,888) 3072x1024 fp16  (read by gemm_mfma)
    //   rt  [39,845,888, 39,944,192) rope table      (read by attn_reg)
    u16*    xh  = (u16*)d_out;
    u16*    wqT = (u16*)((char*)d_out + 33554432);
    float2* rt  = (float2*)((char*)d_out + 39845888);

    rope_table<<<dim3(48), 256, 0, stream>>>(rt);
    cvt_f32_f16<<<dim3(2048), 256, 0, stream>>>(x, xh, 2097152);
    transpose_cvt<<<dim3(96, 32), 256, 0, stream>>>(w_qkv, wqT, 1024, 3072);

    // qkv = xh @ wqT^T   (fp16 in, fp16 out, fp32 MFMA accumulate)
    gemm_mfma<<<dim3(24, 128), 256, 0, stream>>>(xh, 1024, wqT, 1024, qkv, 3072, 1024);
    // attention; O overwrites the q-slots of qkv (stride 3072)
    attn_reg<<<dim3(64, 32), 128, 0, stream>>>(qkv, q_scale, k_scale, rt);
    // out = O @ w_out   (A fp16 q-slots lda=3072, B fp32 direct, C fp32)
    gemm_nn_f32<<<dim3(8, 128), 256, 0, stream>>>(qkv, 3072, w_out, outp, 1024, 1024, 1024);
}

// Round 5
// 924.544 us; speedup vs baseline: 5.4053x; 1.4714x over previous
//
#include <hip/hip_runtime.h>
#include <cstdint>
#include <cstddef>

typedef unsigned short u16;
typedef unsigned int u32;
typedef _Float16 f16;
typedef __attribute__((ext_vector_type(8))) _Float16 f16x8;
typedef __attribute__((ext_vector_type(4))) float f32x4;

#define DEV static __device__ __forceinline__

DEV u16 f2h(float f) { return __builtin_bit_cast(u16, (_Float16)f); }
DEV float h2f(u16 h) { return (float)__builtin_bit_cast(_Float16, h); }
DEV float hlo(u32 w) { return (float)__builtin_bit_cast(_Float16, (u16)(w & 0xffffu)); }
DEV float hhi(u32 w) { return (float)__builtin_bit_cast(_Float16, (u16)(w >> 16)); }
DEV u32 pk2h(float a, float b) { return (u32)f2h(a) | ((u32)f2h(b) << 16); }

#define LOG2E 1.4426950408889634f
#define NEGF (-1e30f)
#define NLOG2F (-0.41524101186092029f)  // -log2(10000)/32

// butterfly sum over 4-lane groups via DPP quad_perm (pure VALU, no LDS pipe)
DEV float qsum4(float x) {
    float y = x + __builtin_bit_cast(float, __builtin_amdgcn_mov_dpp(
                      __builtin_bit_cast(int, x), 0xB1, 0xF, 0xF, true));  // xor 1
    float z = y + __builtin_bit_cast(float, __builtin_amdgcn_mov_dpp(
                      __builtin_bit_cast(int, y), 0x4E, 0xF, 0xF, true));  // xor 2
    return z;
}

// ---------------- rope table: tab[p*32+d] = {cos f, sin f}, f = p*10000^(-d/32) ----------------
__global__ __launch_bounds__(256) void rope_table(float2* __restrict__ tab) {
    int idx = blockIdx.x * 256 + threadIdx.x;
    if (idx >= 384 * 32) return;
    int p = idx >> 5, d = idx & 31;
    float f = (float)p * exp2f(NLOG2F * (float)d);
    tab[idx] = make_float2(cosf(f), sinf(f));
}

// ---------------- fp32 -> fp16 convert (n8 groups of 8) ----------------
__global__ __launch_bounds__(256) void cvt_f32_f16(const float* __restrict__ in,
                                                   u16* __restrict__ out, int n8) {
    int idx = blockIdx.x * 256 + threadIdx.x;
    int stride = gridDim.x * 256;
    for (int i = idx; i < n8; i += stride) {
        const float4* p = (const float4*)(in + (size_t)i * 8);
        float4 v0 = p[0], v1 = p[1];
        uint4 o;
        o.x = pk2h(v0.x, v0.y); o.y = pk2h(v0.z, v0.w);
        o.z = pk2h(v1.x, v1.y); o.w = pk2h(v1.z, v1.w);
        *(uint4*)(out + (size_t)i * 8) = o;
    }
}

// ---------------- fp32 [R][C] -> fp16 transposed [C][R] ----------------
__global__ __launch_bounds__(256) void transpose_cvt(const float* __restrict__ in,
                                                     u16* __restrict__ out, int R, int C) {
    __shared__ u16 t[32][33];
    int rb = blockIdx.y * 32, cb = blockIdx.x * 32;
    int x = threadIdx.x & 31, y = threadIdx.x >> 5;  // y: 0..7
#pragma unroll
    for (int yy = 0; yy < 4; ++yy) {
        int rr = y + yy * 8;
        t[x][rr] = f2h(in[(size_t)(rb + rr) * C + cb + x]);
    }
    __syncthreads();
#pragma unroll
    for (int yy = 0; yy < 4; ++yy) {
        int rr = y + yy * 8;
        out[(size_t)(cb + rr) * R + rb + x] = t[rr][x];
    }
}

// ---------------- MFMA fp16 GEMM (m97 structure): C[M][N] = A[M][K] @ BT[N][K]^T ----------------
// 128x128 tile, 4 waves (2x2 quadrants of 64x64), BK=64, 16x16x32 f16 MFMA.
// LDS tiles [128 rows][64 k] fp16, row stride 128B, st_16x32 XOR swizzle:
//   16B-slot s of row r sits at byte r*128 + (s ^ (r&7))*16.
// global_load_lds writes LINEAR dest (rule #21): the global SOURCE address is
// inverse-swizzled so the swizzled ds_read recovers k = slot*8 correctly.

DEV void gload16(const void* g, void* l) {
    __builtin_amdgcn_global_load_lds(
        (const __attribute__((address_space(1))) unsigned int*)g,
        (__attribute__((address_space(3))) unsigned int*)l, 16, 0, 0);
}

template <bool C_F32>
__global__ __launch_bounds__(256) void gemm_mfma(const u16* __restrict__ A, int lda,
                                                 const u16* __restrict__ BT, int ldb,
                                                 void* __restrict__ Cp, int ldc,
                                                 int K) {
    __shared__ __align__(16) u16 As[128 * 64];
    __shared__ __align__(16) u16 Bs[128 * 64];
    const int tid = threadIdx.x;
    const int w = tid >> 6, l = tid & 63;
    const int m0 = blockIdx.y * 128, n0 = blockIdx.x * 128;
    const int wr = (w >> 1) * 64, wc = (w & 1) * 64;  // wave quadrant origin
    const int r = l & 15, g = l >> 4;

    f32x4 acc[4][4] = {};

    for (int k0 = 0; k0 < K; k0 += 64) {
        __syncthreads();
#pragma unroll
        for (int i = 0; i < 4; ++i) {
            // chunk covers LDS bytes [chunk*1024, +1024): rows chunk*8..chunk*8+7
            int chunk = i * 4 + w;
            int row = chunk * 8 + (l >> 3);
            int ksrc = ((l & 7) ^ (row & 7)) * 8;  // inverse-swizzled source slot
            gload16(A + (size_t)(m0 + row) * lda + k0 + ksrc, &As[chunk * 512]);
            gload16(BT + (size_t)(n0 + row) * ldb + k0 + ksrc, &Bs[chunk * 512]);
        }
        __syncthreads();
#pragma unroll
        for (int kk = 0; kk < 2; ++kk) {
            f16x8 a[4], b[4];
#pragma unroll
            for (int mi = 0; mi < 4; ++mi) {
                int row = wr + mi * 16 + r;
                int byte = row * 128 + (((kk * 4 + g) ^ (row & 7)) << 4);
                a[mi] = *(const f16x8*)((const char*)As + byte);
            }
#pragma unroll
            for (int ni = 0; ni < 4; ++ni) {
                int row = wc + ni * 16 + r;
                int byte = row * 128 + (((kk * 4 + g) ^ (row & 7)) << 4);
                b[ni] = *(const f16x8*)((const char*)Bs + byte);
            }
#pragma unroll
            for (int mi = 0; mi < 4; ++mi)
#pragma unroll
                for (int ni = 0; ni < 4; ++ni)
                    acc[mi][ni] = __builtin_amdgcn_mfma_f32_16x16x32_f16(
                        a[mi], b[ni], acc[mi][ni], 0, 0, 0);
        }
    }

    // C/D layout (m89, dtype-independent): col = lane&15, row = (lane>>4)*4 + reg
#pragma unroll
    for (int mi = 0; mi < 4; ++mi)
#pragma unroll
        for (int ni = 0; ni < 4; ++ni) {
            int row0 = m0 + wr + mi * 16 + g * 4;
            int col  = n0 + wc + ni * 16 + r;
#pragma unroll
            for (int rr = 0; rr < 4; ++rr) {
                size_t idx = (size_t)(row0 + rr) * ldc + col;
                if (C_F32) ((float*)Cp)[idx] = acc[mi][ni][rr];
                else       ((u16*)Cp)[idx]   = f2h(acc[mi][ni][rr]);
            }
        }
}

// ---------------- fp32-VALU GEMM (fallback, proven R2/R4): C = A(f16) @ B(f32) ----------------

DEV int cmap(int c) { return c + ((c >> 5) << 2); }

__global__ __launch_bounds__(256) void gemm_nn_f32(const u16* __restrict__ A, int lda,
                                                   const float* __restrict__ B,
                                                   float* __restrict__ Cp, int ldc,
                                                   int N, int K) {
    __shared__ __align__(16) float As[16][132];   // [k][m]
    __shared__ __align__(16) float Bs[16][140];   // [k][cmap(n)]
    const int tid = threadIdx.x;
    const int m0 = blockIdx.y * 128, n0 = blockIdx.x * 128;
    const int tx = tid & 15, ty = tid >> 4;
    const int txm = cmap(tx * 8);

    const int ar = tid >> 1, ac = (tid & 1) * 8;   // A: 128 rows x 16 cols
    const int br = tid >> 4, bc = (tid & 15) * 8;  // B: 16 rows x 128 cols
    const int bcm = cmap(bc);

    float acc[8][8] = {};

    for (int k0 = 0; k0 < K; k0 += 16) {
        __syncthreads();
        {
            uint4 av = *(const uint4*)(A + (size_t)(m0 + ar) * lda + k0 + ac);
            As[ac + 0][ar] = hlo(av.x); As[ac + 1][ar] = hhi(av.x);
            As[ac + 2][ar] = hlo(av.y); As[ac + 3][ar] = hhi(av.y);
            As[ac + 4][ar] = hlo(av.z); As[ac + 5][ar] = hhi(av.z);
            As[ac + 6][ar] = hlo(av.w); As[ac + 7][ar] = hhi(av.w);
        }
        {
            const float* bp = B + (size_t)(k0 + br) * N + n0 + bc;
            float4 b0 = *(const float4*)bp, b1 = *(const float4*)(bp + 4);
            *(float4*)&Bs[br][bcm]     = b0;
            *(float4*)&Bs[br][bcm + 4] = b1;
        }
        __syncthreads();
#pragma unroll
        for (int kk = 0; kk < 16; ++kk) {
            float4 a0 = *(const float4*)&As[kk][ty * 8];
            float4 a1 = *(const float4*)&As[kk][ty * 8 + 4];
            float4 b0 = *(const float4*)&Bs[kk][txm];
            float4 b1 = *(const float4*)&Bs[kk][txm + 4];
            float a[8] = {a0.x, a0.y, a0.z, a0.w, a1.x, a1.y, a1.z, a1.w};
            float b[8] = {b0.x, b0.y, b0.z, b0.w, b1.x, b1.y, b1.z, b1.w};
#pragma unroll
            for (int i = 0; i < 8; ++i)
#pragma unroll
                for (int j = 0; j < 8; ++j) acc[i][j] += a[i] * b[j];
        }
    }

#pragma unroll
    for (int i = 0; i < 8; ++i) {
        size_t row = (size_t)(m0 + ty * 8 + i);
        float* cp = Cp + row * ldc + n0 + tx * 8;
        *(float4*)cp       = make_float4(acc[i][0], acc[i][1], acc[i][2], acc[i][3]);
        *(float4*)(cp + 4) = make_float4(acc[i][4], acc[i][5], acc[i][6], acc[i][7]);
    }
}

// ---------------- local attention: query-register-tiled (4q x 16d per thread), fp16 qkv ----------------

DEV float hx(const u32* kw, int d) {
    u32 w = kw[d >> 1];
    return (d & 1) ? hhi(w) : hlo(w);
}

// load a 64-elem fp16 row, l2-normalize, scale, rope; write fp32 to dst[0..63]
DEV void rope_row(const u16* __restrict__ src, const float2* __restrict__ r,
                  const float* __restrict__ sc, float topmul, float* dst) {
    u32 kw[32];
    const uint4* p4 = (const uint4*)src;
#pragma unroll
    for (int t = 0; t < 8; ++t) {
        uint4 v = p4[t];
        kw[t * 4 + 0] = v.x; kw[t * 4 + 1] = v.y;
        kw[t * 4 + 2] = v.z; kw[t * 4 + 3] = v.w;
    }
    float ss = 0.f;
#pragma unroll
    for (int t = 0; t < 32; ++t) {
        float a = hlo(kw[t]), b = hhi(kw[t]);
        ss += a * a + b * b;
    }
    float inv = topmul / fmaxf(sqrtf(ss), 1e-12f);
#pragma unroll
    for (int w = 0; w < 8; ++w) {
        float lo[4], hi[4];
#pragma unroll
        for (int t = 0; t < 4; ++t) {
            int d = w * 4 + t;  // < 32
            float2 cn = r[d];
            float x0 = hx(kw, d) * inv * sc[d];
            float x1 = hx(kw, d + 32) * inv * sc[d + 32];
            lo[t] = x0 * cn.x - x1 * cn.y;
            hi[t] = x1 * cn.x + x0 * cn.y;
        }
        *(float4*)(dst + w * 4)      = make_float4(lo[0], lo[1], lo[2], lo[3]);
        *(float4*)(dst + 32 + w * 4) = make_float4(hi[0], hi[1], hi[2], hi[3]);
    }
}

// MODE: 0 = valid iff j >= qi (left block), 1 = all valid, 2 = valid iff j <= qi (right block)
template <int MODE>
DEV void do_chunk(int jc, int qb4, int dg,
                  const float (&q)[4][16], float (&o)[4][16],
                  float (&m)[4], float (&l)[4],
                  const float (*Ksp)[68], const u16 (*Vsp)[72]) {
    float s[4][8];
#pragma unroll
    for (int jj = 0; jj < 8; ++jj) {
        const float4* kr = (const float4*)&Ksp[jc + jj][dg * 16];
        float4 k0 = kr[0], k1 = kr[1], k2 = kr[2], k3 = kr[3];
#pragma unroll
        for (int u = 0; u < 4; ++u) {
            float a0 = q[u][0] * k0.x + q[u][4] * k1.x;
            float a1 = q[u][1] * k0.y + q[u][5] * k1.y;
            float a2 = q[u][2] * k0.z + q[u][6] * k1.z;
            float a3 = q[u][3] * k0.w + q[u][7] * k1.w;
            a0 += q[u][8] * k2.x;  a1 += q[u][9] * k2.y;
            a2 += q[u][10] * k2.z; a3 += q[u][11] * k2.w;
            a0 += q[u][12] * k3.x; a1 += q[u][13] * k3.y;
            a2 += q[u][14] * k3.z; a3 += q[u][15] * k3.w;
            s[u][jj] = (a0 + a1) + (a2 + a3);
        }
    }
    // reduce partial dots across the 4-lane d-groups (bitwise-identical in all 4 lanes)
#pragma unroll
    for (int u = 0; u < 4; ++u)
#pragma unroll
        for (int jj = 0; jj < 8; ++jj) s[u][jj] = qsum4(s[u][jj]);

#pragma unroll
    for (int u = 0; u < 4; ++u) {
        const int qi = qb4 + u;
        float sv[8];
#pragma unroll
        for (int jj = 0; jj < 8; ++jj) {
            int j = jc + jj;
            bool ok = (MODE == 1) || (MODE == 0 ? (j >= qi) : (j <= qi));
            sv[jj] = ok ? s[u][jj] : NEGF;
        }
        float cm = fmaxf(fmaxf(fmaxf(sv[0], sv[1]), fmaxf(sv[2], sv[3])),
                         fmaxf(fmaxf(sv[4], sv[5]), fmaxf(sv[6], sv[7])));
        float mn = fmaxf(m[u], cm);
        float al = exp2f((m[u] - mn) * LOG2E);
        float ps = 0.f;
#pragma unroll
        for (int jj = 0; jj < 8; ++jj) {
            int j = jc + jj;
            bool ok = (MODE == 1) || (MODE == 0 ? (j >= qi) : (j <= qi));
            float p = ok ? exp2f((sv[jj] - mn) * LOG2E) : 0.f;  // explicit 0: NEGF-NEGF trap
            s[u][jj] = p;
            ps += p;
        }
        l[u] = l[u] * al + ps;
        m[u] = mn;
#pragma unroll
        for (int d = 0; d < 16; ++d) o[u][d] *= al;
    }

#pragma unroll
    for (int jj = 0; jj < 8; ++jj) {
        const uint4* vr = (const uint4*)&Vsp[jc + jj][dg * 16];
        uint4 v0 = vr[0], v1 = vr[1];
        float vf[16] = {hlo(v0.x), hhi(v0.x), hlo(v0.y), hhi(v0.y),
                        hlo(v0.z), hhi(v0.z), hlo(v0.w), hhi(v0.w),
                        hlo(v1.x), hhi(v1.x), hlo(v1.y), hhi(v1.y),
                        hlo(v1.z), hhi(v1.z), hlo(v1.w), hhi(v1.w)};
#pragma unroll
        for (int u = 0; u < 4; ++u) {
            float pj = s[u][jj];
#pragma unroll
            for (int d = 0; d < 16; ++d) o[u][d] += pj * vf[d];
        }
    }
}

// launch_bounds (128, 1): 512-VGPR budget. R4's (128,2) made the allocator pick
// 128 VGPRs and spill the q/o accumulators (~270 MB scratch writes/dispatch).
__global__ __launch_bounds__(128, 1) void attn_reg(u16* __restrict__ qkv,
                                                   const float* __restrict__ q_scale,
                                                   const float* __restrict__ k_scale,
                                                   const float2* __restrict__ rt) {
    __shared__ __align__(16) float Ks[128][68];  // 34816 B (also Q staging)
    __shared__ __align__(16) u16  Vs[128][72];   // 18432 B -> total 53248

    const int win = blockIdx.x;
    const int bh  = blockIdx.y;
    const int bi  = bh >> 4, h = bh & 15;
    const int tid = threadIdx.x;
    const int dg  = tid & 3;          // d-slice: dg*16 .. dg*16+15
    const int qb  = tid >> 2;         // query group: queries qb*4 .. qb*4+3
    const int qb4 = qb * 4;
    const int wv  = tid >> 6;         // wave id (wave0: queries 0..63, wave1: 64..127)

    // ---- stage Q (roped, x8, q_scale) through Ks, then read register fragments ----
    {
        const u16* src = qkv + ((size_t)(bi * 8192 + win * 128 + tid)) * 3072 + h * 64;
        rope_row(src, rt + (256 + tid) * 32, q_scale, 8.0f, &Ks[tid][0]);
    }
    __syncthreads();
    float q[4][16];
#pragma unroll
    for (int u = 0; u < 4; ++u) {
        const float4* qr = (const float4*)&Ks[qb4 + u][dg * 16];
#pragma unroll
        for (int w = 0; w < 4; ++w) {
            float4 f = qr[w];
            q[u][w * 4 + 0] = f.x; q[u][w * 4 + 1] = f.y;
            q[u][w * 4 + 2] = f.z; q[u][w * 4 + 3] = f.w;
        }
    }
    float o[4][16];
#pragma unroll
    for (int u = 0; u < 4; ++u)
#pragma unroll
        for (int d = 0; d < 16; ++d) o[u][d] = 0.f;
    float m[4] = {NEGF, NEGF, NEGF, NEGF};
    float l[4] = {0.f, 0.f, 0.f, 0.f};

    for (int c = 0; c < 3; ++c) {
        if (win == 0 && c == 0) continue;
        if (win == 63 && c == 2) continue;
        __syncthreads();
        {
            int t = (win - 1 + c) * 128 + tid;
            const u16* src = qkv + ((size_t)(bi * 8192 + t)) * 3072 + 1024 + h * 64;
            rope_row(src, rt + (c * 128 + tid) * 32, k_scale, 1.0f, &Ks[tid][0]);
            const uint4* vp = (const uint4*)(src + 1024);
            uint4* vd = (uint4*)&Vs[tid][0];
#pragma unroll
            for (int t2 = 0; t2 < 8; ++t2) vd[t2] = vp[t2];
        }
        __syncthreads();

        if (c == 0) {
#pragma unroll 1
            for (int ci = wv * 8; ci < 16; ++ci)
                do_chunk<0>(ci * 8, qb4, dg, q, o, m, l, Ks, Vs);
        } else if (c == 1) {
#pragma unroll 1
            for (int ci = 0; ci < 16; ++ci)
                do_chunk<1>(ci * 8, qb4, dg, q, o, m, l, Ks, Vs);
        } else {
            const int ce = wv ? 16 : 8;
#pragma unroll 1
            for (int ci = 0; ci < ce; ++ci)
                do_chunk<2>(ci * 8, qb4, dg, q, o, m, l, Ks, Vs);
        }
    }

    // ---- epilogue: O back into the q-slots (fp16) ----
#pragma unroll
    for (int u = 0; u < 4; ++u) {
        float linv = 1.0f / l[u];
        u16* orow = qkv + ((size_t)(bi * 8192 + win * 128 + qb4 + u)) * 3072 + h * 64 + dg * 16;
        uint4 c0, c1;
        c0.x = pk2h(o[u][0] * linv,  o[u][1] * linv);
        c0.y = pk2h(o[u][2] * linv,  o[u][3] * linv);
        c0.z = pk2h(o[u][4] * linv,  o[u][5] * linv);
        c0.w = pk2h(o[u][6] * linv,  o[u][7] * linv);
        c1.x = pk2h(o[u][8] * linv,  o[u][9] * linv);
        c1.y = pk2h(o[u][10] * linv, o[u][11] * linv);
        c1.z = pk2h(o[u][12] * linv, o[u][13] * linv);
        c1.w = pk2h(o[u][14] * linv, o[u][15] * linv);
        *(uint4*)orow       = c0;
        *(uint4*)(orow + 8) = c1;
    }
}

// ---------------- host launcher ----------------

extern "C" void kernel_launch(void* const* d_in, const int* in_sizes, int n_in,
                              void* d_out, int out_size, void* d_ws, size_t ws_size,
                              hipStream_t stream) {
    // Inputs fp32; OUTPUT IS FP32 (harness reads d_out as float32).
    const float* x       = (const float*)d_in[0];  // [16384, 1024]
    const float* w_qkv   = (const float*)d_in[1];  // [1024, 3072]
    const float* w_out   = (const float*)d_in[2];  // [1024, 1024]
    const float* q_scale = (const float*)d_in[3];  // [64]
    const float* k_scale = (const float*)d_in[4];  // [64]
    float* outp = (float*)d_out;

    // ws: qkv fp16 = 100,663,296 B (validated extent). woT (2 MB) goes in the ws
    // tail ONLY if ws_size proves it exists; otherwise fp32-VALU fallback for GEMM2.
    u16* qkv = (u16*)d_ws;
    const size_t QKV_BYTES = 100663296;
    const size_t WOT_BYTES = 2097152;
    bool ws_has_wot = (ws_size >= QKV_BYTES + WOT_BYTES);
    u16* woT = (u16*)((char*)d_ws + QKV_BYTES);

    // d_out staging, all consumed before the final GEMM writes d_out:
    //   xh  [0, 33,554,432)          16384x1024 fp16  (read by gemm_mfma #1)
    //   wqT [33,554,432, 39,845,888)  3072x1024 fp16  (read by gemm_mfma #1)
    //   rt  [39,845,888, 39,944,192)  rope table      (read by attn_reg)
    u16*    xh  = (u16*)d_out;
    u16*    wqT = (u16*)((char*)d_out + 33554432);
    float2* rt  = (float2*)((char*)d_out + 39845888);

    rope_table<<<dim3(48), 256, 0, stream>>>(rt);
    cvt_f32_f16<<<dim3(2048), 256, 0, stream>>>(x, xh, 2097152);
    transpose_cvt<<<dim3(96, 32), 256, 0, stream>>>(w_qkv, wqT, 1024, 3072);
    if (ws_has_wot)
        transpose_cvt<<<dim3(32, 32), 256, 0, stream>>>(w_out, woT, 1024, 1024);

    // qkv = xh @ wqT^T   (fp16 in, fp16 out, fp32 MFMA accumulate)
    gemm_mfma<false><<<dim3(24, 128), 256, 0, stream>>>(xh, 1024, wqT, 1024, qkv, 3072, 1024);
    // attention; O overwrites the q-slots of qkv (stride 3072)
    attn_reg<<<dim3(64, 32), 128, 0, stream>>>(qkv, q_scale, k_scale, rt);
    // out = O @ w_out
    if (ws_has_wot)
        gemm_mfma<true><<<dim3(8, 128), 256, 0, stream>>>(qkv, 3072, woT, 1024, outp, 1024, 1024);
    else
        gemm_nn_f32<<<dim3(8, 128), 256, 0, stream>>>(qkv, 3072, w_out, outp, 1024, 1024, 1024);
}

// Round 6
// 448.961 us; speedup vs baseline: 11.1311x; 2.0593x over previous
//
#include <hip/hip_runtime.h>
#include <cstdint>
#include <cstddef>

typedef unsigned short u16;
typedef unsigned int u32;
typedef _Float16 f16;
typedef __attribute__((ext_vector_type(8))) _Float16 f16x8;
typedef __attribute__((ext_vector_type(4))) float f32x4;

#define DEV static __device__ __forceinline__

DEV u16 f2h(float f) { return __builtin_bit_cast(u16, (_Float16)f); }
DEV float h2f(u16 h) { return (float)__builtin_bit_cast(_Float16, h); }
DEV float hlo(u32 w) { return (float)__builtin_bit_cast(_Float16, (u16)(w & 0xffffu)); }
DEV float hhi(u32 w) { return (float)__builtin_bit_cast(_Float16, (u16)(w >> 16)); }
DEV u32 pk2h(float a, float b) { return (u32)f2h(a) | ((u32)f2h(b) << 16); }

#define LOG2E 1.4426950408889634f
#define NEGF (-1e30f)
#define NLOG2F (-0.41524101186092029f)  // -log2(10000)/32

// DPP reductions over the 16-lane groups (lanes g*16 .. g*16+15). quad_perm
// 0xB1/0x4E validated since R2; 0x141 row_half_mirror, 0x140 row_mirror.
DEV float dppmax16(float x) {
    float y;
    y = __builtin_bit_cast(float, __builtin_amdgcn_mov_dpp(__builtin_bit_cast(int, x), 0xB1, 0xF, 0xF, true)); x = fmaxf(x, y);
    y = __builtin_bit_cast(float, __builtin_amdgcn_mov_dpp(__builtin_bit_cast(int, x), 0x4E, 0xF, 0xF, true)); x = fmaxf(x, y);
    y = __builtin_bit_cast(float, __builtin_amdgcn_mov_dpp(__builtin_bit_cast(int, x), 0x141, 0xF, 0xF, true)); x = fmaxf(x, y);
    y = __builtin_bit_cast(float, __builtin_amdgcn_mov_dpp(__builtin_bit_cast(int, x), 0x140, 0xF, 0xF, true)); x = fmaxf(x, y);
    return x;
}
DEV float dppsum16(float x) {
    float y;
    y = __builtin_bit_cast(float, __builtin_amdgcn_mov_dpp(__builtin_bit_cast(int, x), 0xB1, 0xF, 0xF, true)); x += y;
    y = __builtin_bit_cast(float, __builtin_amdgcn_mov_dpp(__builtin_bit_cast(int, x), 0x4E, 0xF, 0xF, true)); x += y;
    y = __builtin_bit_cast(float, __builtin_amdgcn_mov_dpp(__builtin_bit_cast(int, x), 0x141, 0xF, 0xF, true)); x += y;
    y = __builtin_bit_cast(float, __builtin_amdgcn_mov_dpp(__builtin_bit_cast(int, x), 0x140, 0xF, 0xF, true)); x += y;
    return x;
}

// ---------------- rope table: tab[p*32+d] = {cos f, sin f}, f = p*10000^(-d/32) ----------------
__global__ __launch_bounds__(256) void rope_table(float2* __restrict__ tab) {
    int idx = blockIdx.x * 256 + threadIdx.x;
    if (idx >= 384 * 32) return;
    int p = idx >> 5, d = idx & 31;
    float f = (float)p * exp2f(NLOG2F * (float)d);
    tab[idx] = make_float2(cosf(f), sinf(f));
}

// ---------------- fp32 -> fp16 convert (n8 groups of 8) ----------------
__global__ __launch_bounds__(256) void cvt_f32_f16(const float* __restrict__ in,
                                                   u16* __restrict__ out, int n8) {
    int idx = blockIdx.x * 256 + threadIdx.x;
    int stride = gridDim.x * 256;
    for (int i = idx; i < n8; i += stride) {
        const float4* p = (const float4*)(in + (size_t)i * 8);
        float4 v0 = p[0], v1 = p[1];
        uint4 o;
        o.x = pk2h(v0.x, v0.y); o.y = pk2h(v0.z, v0.w);
        o.z = pk2h(v1.x, v1.y); o.w = pk2h(v1.z, v1.w);
        *(uint4*)(out + (size_t)i * 8) = o;
    }
}

// ---------------- fp32 [R][C] -> fp16 transposed [C][R] ----------------
__global__ __launch_bounds__(256) void transpose_cvt(const float* __restrict__ in,
                                                     u16* __restrict__ out, int R, int C) {
    __shared__ u16 t[32][33];
    int rb = blockIdx.y * 32, cb = blockIdx.x * 32;
    int x = threadIdx.x & 31, y = threadIdx.x >> 5;  // y: 0..7
#pragma unroll
    for (int yy = 0; yy < 4; ++yy) {
        int rr = y + yy * 8;
        t[x][rr] = f2h(in[(size_t)(rb + rr) * C + cb + x]);
    }
    __syncthreads();
#pragma unroll
    for (int yy = 0; yy < 4; ++yy) {
        int rr = y + yy * 8;
        out[(size_t)(cb + rr) * R + rb + x] = t[rr][x];
    }
}

// ---------------- MFMA fp16 GEMM (validated R4/R5): C[M][N] = A[M][K] @ BT[N][K]^T ----------------

DEV void gload16(const void* g, void* l) {
    __builtin_amdgcn_global_load_lds(
        (const __attribute__((address_space(1))) unsigned int*)g,
        (__attribute__((address_space(3))) unsigned int*)l, 16, 0, 0);
}

template <bool C_F32>
__global__ __launch_bounds__(256) void gemm_mfma(const u16* __restrict__ A, int lda,
                                                 const u16* __restrict__ BT, int ldb,
                                                 void* __restrict__ Cp, int ldc,
                                                 int K) {
    __shared__ __align__(16) u16 As[128 * 64];
    __shared__ __align__(16) u16 Bs[128 * 64];
    const int tid = threadIdx.x;
    const int w = tid >> 6, l = tid & 63;
    const int m0 = blockIdx.y * 128, n0 = blockIdx.x * 128;
    const int wr = (w >> 1) * 64, wc = (w & 1) * 64;
    const int r = l & 15, g = l >> 4;

    f32x4 acc[4][4] = {};

    for (int k0 = 0; k0 < K; k0 += 64) {
        __syncthreads();
#pragma unroll
        for (int i = 0; i < 4; ++i) {
            int chunk = i * 4 + w;
            int row = chunk * 8 + (l >> 3);
            int ksrc = ((l & 7) ^ (row & 7)) * 8;
            gload16(A + (size_t)(m0 + row) * lda + k0 + ksrc, &As[chunk * 512]);
            gload16(BT + (size_t)(n0 + row) * ldb + k0 + ksrc, &Bs[chunk * 512]);
        }
        __syncthreads();
#pragma unroll
        for (int kk = 0; kk < 2; ++kk) {
            f16x8 a[4], b[4];
#pragma unroll
            for (int mi = 0; mi < 4; ++mi) {
                int row = wr + mi * 16 + r;
                int byte = row * 128 + (((kk * 4 + g) ^ (row & 7)) << 4);
                a[mi] = *(const f16x8*)((const char*)As + byte);
            }
#pragma unroll
            for (int ni = 0; ni < 4; ++ni) {
                int row = wc + ni * 16 + r;
                int byte = row * 128 + (((kk * 4 + g) ^ (row & 7)) << 4);
                b[ni] = *(const f16x8*)((const char*)Bs + byte);
            }
#pragma unroll
            for (int mi = 0; mi < 4; ++mi)
#pragma unroll
                for (int ni = 0; ni < 4; ++ni)
                    acc[mi][ni] = __builtin_amdgcn_mfma_f32_16x16x32_f16(
                        a[mi], b[ni], acc[mi][ni], 0, 0, 0);
        }
    }

#pragma unroll
    for (int mi = 0; mi < 4; ++mi)
#pragma unroll
        for (int ni = 0; ni < 4; ++ni) {
            int row0 = m0 + wr + mi * 16 + g * 4;
            int col  = n0 + wc + ni * 16 + r;
#pragma unroll
            for (int rr = 0; rr < 4; ++rr) {
                size_t idx = (size_t)(row0 + rr) * ldc + col;
                if (C_F32) ((float*)Cp)[idx] = acc[mi][ni][rr];
                else       ((u16*)Cp)[idx]   = f2h(acc[mi][ni][rr]);
            }
        }
}

// ---------------- fp32-VALU GEMM fallback (proven R2/R4): C = A(f16) @ B(f32) ----------------

DEV int cmap(int c) { return c + ((c >> 5) << 2); }

__global__ __launch_bounds__(256) void gemm_nn_f32(const u16* __restrict__ A, int lda,
                                                   const float* __restrict__ B,
                                                   float* __restrict__ Cp, int ldc,
                                                   int N, int K) {
    __shared__ __align__(16) float As[16][132];
    __shared__ __align__(16) float Bs[16][140];
    const int tid = threadIdx.x;
    const int m0 = blockIdx.y * 128, n0 = blockIdx.x * 128;
    const int tx = tid & 15, ty = tid >> 4;
    const int txm = cmap(tx * 8);

    const int ar = tid >> 1, ac = (tid & 1) * 8;
    const int br = tid >> 4, bc = (tid & 15) * 8;
    const int bcm = cmap(bc);

    float acc[8][8] = {};

    for (int k0 = 0; k0 < K; k0 += 16) {
        __syncthreads();
        {
            uint4 av = *(const uint4*)(A + (size_t)(m0 + ar) * lda + k0 + ac);
            As[ac + 0][ar] = hlo(av.x); As[ac + 1][ar] = hhi(av.x);
            As[ac + 2][ar] = hlo(av.y); As[ac + 3][ar] = hhi(av.y);
            As[ac + 4][ar] = hlo(av.z); As[ac + 5][ar] = hhi(av.z);
            As[ac + 6][ar] = hlo(av.w); As[ac + 7][ar] = hhi(av.w);
        }
        {
            const float* bp = B + (size_t)(k0 + br) * N + n0 + bc;
            float4 b0 = *(const float4*)bp, b1 = *(const float4*)(bp + 4);
            *(float4*)&Bs[br][bcm]     = b0;
            *(float4*)&Bs[br][bcm + 4] = b1;
        }
        __syncthreads();
#pragma unroll
        for (int kk = 0; kk < 16; ++kk) {
            float4 a0 = *(const float4*)&As[kk][ty * 8];
            float4 a1 = *(const float4*)&As[kk][ty * 8 + 4];
            float4 b0 = *(const float4*)&Bs[kk][txm];
            float4 b1 = *(const float4*)&Bs[kk][txm + 4];
            float a[8] = {a0.x, a0.y, a0.z, a0.w, a1.x, a1.y, a1.z, a1.w};
            float b[8] = {b0.x, b0.y, b0.z, b0.w, b1.x, b1.y, b1.z, b1.w};
#pragma unroll
            for (int i = 0; i < 8; ++i)
#pragma unroll
                for (int j = 0; j < 8; ++j) acc[i][j] += a[i] * b[j];
        }
    }

#pragma unroll
    for (int i = 0; i < 8; ++i) {
        size_t row = (size_t)(m0 + ty * 8 + i);
        float* cp = Cp + row * ldc + n0 + tx * 8;
        *(float4*)cp       = make_float4(acc[i][0], acc[i][1], acc[i][2], acc[i][3]);
        *(float4*)(cp + 4) = make_float4(acc[i][4], acc[i][5], acc[i][6], acc[i][7]);
    }
}

// ---------------- MFMA local attention ----------------
// 1 block = (bh, win). 256 threads / 4 waves. Wave w owns query rows [32w, 32w+32)
// of the window; context (384 keys) processed in j-chunks of 64.
// LDS (all f16 rows padded to 144 B = 16B-aligned, 2-way banks):
//   [0,      18432): Q staging [128][72]  -> reused as per-wave P [32][72] regions
//                    (wave w only touches rows [32w,32w+32) in both uses -> wave-local)
//   [18432,  27648): K chunk [64][72]  (roped, normalized, k_scale)
//   [27648,  36864): V^T chunk [64][72]  (Vt[d][j])
// MFMA fragment facts reused from validated gemm_mfma:
//   A/B-frag: row = base + (lane&15), 16B k-slice slot = lane>>4
//   C/D: col = lane&15, row = (lane>>4)*4 + reg

DEV float hx(const u32* kw, int d) {
    u32 w = kw[d >> 1];
    return (d & 1) ? hhi(w) : hlo(w);
}

// full-row rope -> packed f16 (32 u32 per 64-d row)
DEV void rope_row_h(const u16* __restrict__ src, const float2* __restrict__ r,
                    const float* __restrict__ sc, float topmul, u32* __restrict__ dst) {
    u32 kw[32];
    const uint4* p4 = (const uint4*)src;
#pragma unroll
    for (int t = 0; t < 8; ++t) {
        uint4 v = p4[t];
        kw[t*4] = v.x; kw[t*4+1] = v.y; kw[t*4+2] = v.z; kw[t*4+3] = v.w;
    }
    float ss = 0.f;
#pragma unroll
    for (int t = 0; t < 32; ++t) { float a = hlo(kw[t]), b = hhi(kw[t]); ss += a*a + b*b; }
    float inv = topmul / fmaxf(sqrtf(ss), 1e-12f);
#pragma unroll
    for (int d2 = 0; d2 < 32; d2 += 2) {
        float2 c0 = r[d2], c1 = r[d2 + 1];
        float x00 = hx(kw, d2)      * inv * sc[d2];
        float x01 = hx(kw, d2 + 32) * inv * sc[d2 + 32];
        float x10 = hx(kw, d2 + 1)  * inv * sc[d2 + 1];
        float x11 = hx(kw, d2 + 33) * inv * sc[d2 + 33];
        dst[d2 >> 1]        = pk2h(x00 * c0.x - x01 * c0.y, x10 * c1.x - x11 * c1.y);
        dst[16 + (d2 >> 1)] = pk2h(x01 * c0.x + x00 * c0.y, x11 * c1.x + x10 * c1.y);
    }
}

#define KOFF_B  18432
#define VTOFF_B 27648

__global__ __launch_bounds__(256, 2) void attn_mfma(u16* __restrict__ qkv,
                                                    const float* __restrict__ q_scale,
                                                    const float* __restrict__ k_scale,
                                                    const float2* __restrict__ rt) {
    __shared__ __align__(16) char SMB[36864];

    const int win = blockIdx.x, bh = blockIdx.y;
    const int bi = bh >> 4, h = bh & 15;
    const int tid = threadIdx.x;
    const int w = tid >> 6, l = tid & 63;
    const int r = l & 15, g = l >> 4;

    // ---- stage Q (rope, x8, q_scale) into rows [0,128) ----
    if (tid < 128) {
        const u16* src = qkv + ((size_t)(bi * 8192 + win * 128 + tid)) * 3072 + h * 64;
        rope_row_h(src, rt + (256 + tid) * 32, q_scale, 8.0f, (u32*)(SMB + tid * 144));
    }
    __syncthreads();

    // ---- per-wave Q fragments (rows 32w + mi*16 + r) ----
    f16x8 aq[2][2];
#pragma unroll
    for (int mi = 0; mi < 2; ++mi)
#pragma unroll
        for (int kk = 0; kk < 2; ++kk)
            aq[mi][kk] = *(const f16x8*)(SMB + (w * 32 + mi * 16 + r) * 144 + (kk * 4 + g) * 16);

    f32x4 acc_o[2][4] = {};
    float m[2][4], lsum[2][4];
#pragma unroll
    for (int mi = 0; mi < 2; ++mi)
#pragma unroll
        for (int rr = 0; rr < 4; ++rr) { m[mi][rr] = NEGF; lsum[mi][rr] = 0.f; }

    const int cl = (win == 0) ? 2 : 0;
    const int ch = (win == 63) ? 3 : 5;
    const int wlo = w >> 1;        // wave's valid chunk range [wlo, wlo+4]
    const int whi = wlo + 4;

    for (int c = cl; c <= ch; ++c) {
        __syncthreads();  // previous chunk's LDS reads complete

        // ---- stage K chunk (rope, half-row per thread; waves 0,1) ----
        if (tid < 128) {
            int jrow = tid >> 1, hf = tid & 1;
            const u16* src = qkv + ((size_t)(bi * 8192 + (win - 1) * 128 + c * 64 + jrow)) * 3072
                             + 1024 + h * 64;
            u32 kw[32];
            const uint4* p4 = (const uint4*)src;
#pragma unroll
            for (int t = 0; t < 8; ++t) {
                uint4 v = p4[t];
                kw[t*4] = v.x; kw[t*4+1] = v.y; kw[t*4+2] = v.z; kw[t*4+3] = v.w;
            }
            float ss = 0.f;
#pragma unroll
            for (int t = 0; t < 32; ++t) { float a = hlo(kw[t]), b = hhi(kw[t]); ss += a*a + b*b; }
            float inv = 1.0f / fmaxf(sqrtf(ss), 1e-12f);
            const float2* rr_ = rt + (c * 64 + jrow) * 32;
            u32* dst = (u32*)(SMB + KOFF_B + jrow * 144 + hf * 64);
#pragma unroll
            for (int d2 = 0; d2 < 32; d2 += 2) {
                float2 c0 = rr_[d2], c1 = rr_[d2 + 1];
                float x00 = hx(kw, d2)      * inv * k_scale[d2];
                float x01 = hx(kw, d2 + 32) * inv * k_scale[d2 + 32];
                float x10 = hx(kw, d2 + 1)  * inv * k_scale[d2 + 1];
                float x11 = hx(kw, d2 + 33) * inv * k_scale[d2 + 33];
                float v0 = hf ? (x01 * c0.x + x00 * c0.y) : (x00 * c0.x - x01 * c0.y);
                float v1 = hf ? (x11 * c1.x + x10 * c1.y) : (x10 * c1.x - x11 * c1.y);
                dst[d2 >> 1] = pk2h(v0, v1);
            }
        } else {
            // ---- stage V^T chunk (half-row per thread; waves 2,3) ----
            int tt = tid - 128;
            int jrow = tt >> 1, hf = tt & 1;
            const u16* src = qkv + ((size_t)(bi * 8192 + (win - 1) * 128 + c * 64 + jrow)) * 3072
                             + 2048 + h * 64 + hf * 32;
            u32 vw[16];
            const uint4* p4 = (const uint4*)src;
#pragma unroll
            for (int t = 0; t < 4; ++t) {
                uint4 v = p4[t];
                vw[t*4] = v.x; vw[t*4+1] = v.y; vw[t*4+2] = v.z; vw[t*4+3] = v.w;
            }
#pragma unroll
            for (int d2 = 0; d2 < 32; ++d2) {
                u16 val = (d2 & 1) ? (u16)(vw[d2 >> 1] >> 16) : (u16)(vw[d2 >> 1] & 0xffffu);
                *(u16*)(SMB + VTOFF_B + (hf * 32 + d2) * 144 + jrow * 2) = val;
            }
        }
        __syncthreads();  // staging visible

        if (c < wlo || c > whi) continue;

        // ---- S = Q K^T for this wave's 32 rows x 64 chunk cols ----
        f32x4 acc_s[2][4] = {};
#pragma unroll
        for (int kk = 0; kk < 2; ++kk) {
#pragma unroll
            for (int nj = 0; nj < 4; ++nj) {
                f16x8 bk = *(const f16x8*)(SMB + KOFF_B + (nj * 16 + r) * 144 + (kk * 4 + g) * 16);
#pragma unroll
                for (int mi = 0; mi < 2; ++mi)
                    acc_s[mi][nj] = __builtin_amdgcn_mfma_f32_16x16x32_f16(
                        aq[mi][kk], bk, acc_s[mi][nj], 0, 0, 0);
            }
        }

        // ---- mask + online softmax (wave-local; per lane: rows g*4+rr, cols r) ----
        float al_[2][4];
#pragma unroll
        for (int mi = 0; mi < 2; ++mi) {
#pragma unroll
            for (int rr = 0; rr < 4; ++rr) {
                const int qiw = w * 32 + mi * 16 + g * 4 + rr;
                float sv[4];
#pragma unroll
                for (int nj = 0; nj < 4; ++nj) {
                    int jp = c * 64 + nj * 16 + r;
                    bool ok = (jp >= qiw) && (jp <= qiw + 256);
                    sv[nj] = ok ? acc_s[mi][nj][rr] : NEGF;
                }
                float cm = fmaxf(fmaxf(sv[0], sv[1]), fmaxf(sv[2], sv[3]));
                cm = dppmax16(cm);
                float mn = fmaxf(m[mi][rr], cm);
                float al = exp2f((m[mi][rr] - mn) * LOG2E);
                float ps = 0.f;
#pragma unroll
                for (int nj = 0; nj < 4; ++nj) {
                    int jp = c * 64 + nj * 16 + r;
                    bool ok = (jp >= qiw) && (jp <= qiw + 256);
                    float p = ok ? exp2f((sv[nj] - mn) * LOG2E) : 0.f;  // explicit 0: NEGF trap
                    // write P (f16) into this wave's region (aliases its own Q rows)
                    *(u16*)(SMB + w * 4608 + (mi * 16 + g * 4 + rr) * 144 + (nj * 16 + r) * 2) = f2h(p);
                    ps += p;
                }
                ps = dppsum16(ps);
                lsum[mi][rr] = lsum[mi][rr] * al + ps;
                m[mi][rr] = mn;
                al_[mi][rr] = al;
            }
        }
        // rescale O
#pragma unroll
        for (int mi = 0; mi < 2; ++mi)
#pragma unroll
            for (int ni = 0; ni < 4; ++ni)
#pragma unroll
                for (int rr = 0; rr < 4; ++rr)
                    acc_o[mi][ni][rr] *= al_[mi][rr];

        // ---- O += P V  (A = P from LDS, BT = Vt) ----
#pragma unroll
        for (int kkj = 0; kkj < 2; ++kkj) {
            f16x8 pa[2];
#pragma unroll
            for (int mi = 0; mi < 2; ++mi)
                pa[mi] = *(const f16x8*)(SMB + w * 4608 + (mi * 16 + r) * 144 + (kkj * 4 + g) * 16);
#pragma unroll
            for (int ni = 0; ni < 4; ++ni) {
                f16x8 bv = *(const f16x8*)(SMB + VTOFF_B + (ni * 16 + r) * 144 + (kkj * 4 + g) * 16);
#pragma unroll
                for (int mi = 0; mi < 2; ++mi)
                    acc_o[mi][ni] = __builtin_amdgcn_mfma_f32_16x16x32_f16(
                        pa[mi], bv, acc_o[mi][ni], 0, 0, 0);
            }
        }
    }

    // ---- epilogue: O/l back into the q-slots (fp16) ----
#pragma unroll
    for (int mi = 0; mi < 2; ++mi) {
        float linv[4];
#pragma unroll
        for (int rr = 0; rr < 4; ++rr) linv[rr] = 1.0f / lsum[mi][rr];
#pragma unroll
        for (int ni = 0; ni < 4; ++ni) {
#pragma unroll
            for (int rr = 0; rr < 4; ++rr) {
                int q = win * 128 + w * 32 + mi * 16 + g * 4 + rr;
                int d = ni * 16 + r;
                qkv[((size_t)(bi * 8192 + q)) * 3072 + h * 64 + d] = f2h(acc_o[mi][ni][rr] * linv[rr]);
            }
        }
    }
}

// ---------------- host launcher ----------------

extern "C" void kernel_launch(void* const* d_in, const int* in_sizes, int n_in,
                              void* d_out, int out_size, void* d_ws, size_t ws_size,
                              hipStream_t stream) {
    const float* x       = (const float*)d_in[0];  // [16384, 1024]
    const float* w_qkv   = (const float*)d_in[1];  // [1024, 3072]
    const float* w_out   = (const float*)d_in[2];  // [1024, 1024]
    const float* q_scale = (const float*)d_in[3];  // [64]
    const float* k_scale = (const float*)d_in[4];  // [64]
    float* outp = (float*)d_out;

    u16* qkv = (u16*)d_ws;
    const size_t QKV_BYTES = 100663296;
    const size_t WOT_BYTES = 2097152;
    bool ws_has_wot = (ws_size >= QKV_BYTES + WOT_BYTES);
    u16* woT = (u16*)((char*)d_ws + QKV_BYTES);

    // d_out staging, all consumed before the final GEMM writes d_out:
    u16*    xh  = (u16*)d_out;
    u16*    wqT = (u16*)((char*)d_out + 33554432);
    float2* rt  = (float2*)((char*)d_out + 39845888);

    rope_table<<<dim3(48), 256, 0, stream>>>(rt);
    cvt_f32_f16<<<dim3(2048), 256, 0, stream>>>(x, xh, 2097152);
    transpose_cvt<<<dim3(96, 32), 256, 0, stream>>>(w_qkv, wqT, 1024, 3072);
    if (ws_has_wot)
        transpose_cvt<<<dim3(32, 32), 256, 0, stream>>>(w_out, woT, 1024, 1024);

    // qkv = xh @ wqT^T
    gemm_mfma<false><<<dim3(24, 128), 256, 0, stream>>>(xh, 1024, wqT, 1024, qkv, 3072, 1024);
    // attention (MFMA); O overwrites the q-slots of qkv
    attn_mfma<<<dim3(64, 32), 256, 0, stream>>>(qkv, q_scale, k_scale, rt);
    // out = O @ w_out
    if (ws_has_wot)
        gemm_mfma<true><<<dim3(8, 128), 256, 0, stream>>>(qkv, 3072, woT, 1024, outp, 1024, 1024);
    else
        gemm_nn_f32<<<dim3(8, 128), 256, 0, stream>>>(qkv, 3072, w_out, outp, 1024, 1024, 1024);
}

// Round 7
// 406.386 us; speedup vs baseline: 12.2972x; 1.1048x over previous
//
#include <hip/hip_runtime.h>
#include <cstdint>
#include <cstddef>

typedef unsigned short u16;
typedef unsigned int u32;
typedef _Float16 f16;
typedef __attribute__((ext_vector_type(8))) _Float16 f16x8;
typedef __attribute__((ext_vector_type(4))) float f32x4;

#define DEV static __device__ __forceinline__

DEV u16 f2h(float f) { return __builtin_bit_cast(u16, (_Float16)f); }
DEV float hlo(u32 w) { return (float)__builtin_bit_cast(_Float16, (u16)(w & 0xffffu)); }
DEV float hhi(u32 w) { return (float)__builtin_bit_cast(_Float16, (u16)(w >> 16)); }
DEV u32 pk2h(float a, float b) { return (u32)f2h(a) | ((u32)f2h(b) << 16); }

#define LOG2E 1.4426950408889634f
#define NEGF (-1e30f)
#define NLOG2F (-0.41524101186092029)  // -log2(10000)/32 (double)

// DPP reductions over 16-lane rows (validated R6)
DEV float dppmax16(float x) {
    float y;
    y = __builtin_bit_cast(float, __builtin_amdgcn_mov_dpp(__builtin_bit_cast(int, x), 0xB1, 0xF, 0xF, true)); x = fmaxf(x, y);
    y = __builtin_bit_cast(float, __builtin_amdgcn_mov_dpp(__builtin_bit_cast(int, x), 0x4E, 0xF, 0xF, true)); x = fmaxf(x, y);
    y = __builtin_bit_cast(float, __builtin_amdgcn_mov_dpp(__builtin_bit_cast(int, x), 0x141, 0xF, 0xF, true)); x = fmaxf(x, y);
    y = __builtin_bit_cast(float, __builtin_amdgcn_mov_dpp(__builtin_bit_cast(int, x), 0x140, 0xF, 0xF, true)); x = fmaxf(x, y);
    return x;
}
DEV float dppsum16(float x) {
    float y;
    y = __builtin_bit_cast(float, __builtin_amdgcn_mov_dpp(__builtin_bit_cast(int, x), 0xB1, 0xF, 0xF, true)); x += y;
    y = __builtin_bit_cast(float, __builtin_amdgcn_mov_dpp(__builtin_bit_cast(int, x), 0x4E, 0xF, 0xF, true)); x += y;
    y = __builtin_bit_cast(float, __builtin_amdgcn_mov_dpp(__builtin_bit_cast(int, x), 0x141, 0xF, 0xF, true)); x += y;
    y = __builtin_bit_cast(float, __builtin_amdgcn_mov_dpp(__builtin_bit_cast(int, x), 0x140, 0xF, 0xF, true)); x += y;
    return x;
}

// ---------------- global rope table: tab[p*32+d] = {cos,sin}(p * 10000^(-d/32)), p < 8320 ----------------
// Global phases (q: nn+128, k: nn) reach ~8300 rad; compute in double with mod-2pi
// reduction so the RELATIVE rotation (what S depends on) is exact to ~1e-8.
__global__ __launch_bounds__(256) void rope_table2(float2* __restrict__ tab) {
    int idx = blockIdx.x * 256 + threadIdx.x;
    if (idx >= 8320 * 32) return;
    int p = idx >> 5, d = idx & 31;
    double th = (double)p * exp2((double)d * NLOG2F);
    th = fmod(th, 6.283185307179586476925287);
    tab[idx] = make_float2((float)cos(th), (float)sin(th));
}

// ---------------- fp32 -> fp16 convert ----------------
__global__ __launch_bounds__(256) void cvt_f32_f16(const float* __restrict__ in,
                                                   u16* __restrict__ out, int n8) {
    int idx = blockIdx.x * 256 + threadIdx.x;
    int stride = gridDim.x * 256;
    for (int i = idx; i < n8; i += stride) {
        const float4* p = (const float4*)(in + (size_t)i * 8);
        float4 v0 = p[0], v1 = p[1];
        uint4 o;
        o.x = pk2h(v0.x, v0.y); o.y = pk2h(v0.z, v0.w);
        o.z = pk2h(v1.x, v1.y); o.w = pk2h(v1.z, v1.w);
        *(uint4*)(out + (size_t)i * 8) = o;
    }
}

// ---------------- fp32 [R][C] -> fp16 transposed [C][R] ----------------
__global__ __launch_bounds__(256) void transpose_cvt(const float* __restrict__ in,
                                                     u16* __restrict__ out, int R, int C) {
    __shared__ u16 t[32][33];
    int rb = blockIdx.y * 32, cb = blockIdx.x * 32;
    int x = threadIdx.x & 31, y = threadIdx.x >> 5;
#pragma unroll
    for (int yy = 0; yy < 4; ++yy) {
        int rr = y + yy * 8;
        t[x][rr] = f2h(in[(size_t)(rb + rr) * C + cb + x]);
    }
    __syncthreads();
#pragma unroll
    for (int yy = 0; yy < 4; ++yy) {
        int rr = y + yy * 8;
        out[(size_t)(cb + rr) * R + rb + x] = t[rr][x];
    }
}

// ---------------- shared MFMA GEMM machinery (validated R4-R6) ----------------

DEV void gload16(const void* g, void* l) {
    __builtin_amdgcn_global_load_lds(
        (const __attribute__((address_space(1))) unsigned int*)g,
        (__attribute__((address_space(3))) unsigned int*)l, 16, 0, 0);
}

// ---------------- GEMM1 + fused qkv epilogue ----------------
// C = xh[16384x1024] @ wqT[3072x1024]^T. Instead of writing raw qkv:
//   cols [0,1024)    q: l2norm*8*q_scale, rope(phase nn+128)  -> qk[row][col]   (ld 2048)
//   cols [1024,2048) k: l2norm*k_scale,   rope(phase nn)      -> qk[row][col]
//   cols [2048,3072) v: raw fp16, TRANSPOSED -> vt[(bi*16+h)*64+d][nn]
// Wave quadrant (wc) = exactly one head (64 cols): row norm = dppsum16 over the
// 16 r-lanes; rope pairs (d,d+32) = (ni0,ni2)/(ni1,ni3) are lane-local.
// v scattered u16 stores: each block's d x n tile is line-dense -> L2 merges.
__global__ __launch_bounds__(256) void gemm_qkv(const u16* __restrict__ A,
                                                const u16* __restrict__ BT,
                                                u16* __restrict__ qk,
                                                u16* __restrict__ vt,
                                                const float* __restrict__ q_scale,
                                                const float* __restrict__ k_scale,
                                                const float2* __restrict__ rt2) {
    __shared__ __align__(16) u16 As[128 * 64];
    __shared__ __align__(16) u16 Bs[128 * 64];
    const int tid = threadIdx.x;
    const int w = tid >> 6, l = tid & 63;
    const int m0 = blockIdx.y * 128, n0 = blockIdx.x * 128;
    const int wr = (w >> 1) * 64, wc = (w & 1) * 64;
    const int r = l & 15, g = l >> 4;

    f32x4 acc[4][4] = {};

    for (int k0 = 0; k0 < 1024; k0 += 64) {
        __syncthreads();
#pragma unroll
        for (int i = 0; i < 4; ++i) {
            int chunk = i * 4 + w;
            int row = chunk * 8 + (l >> 3);
            int ksrc = ((l & 7) ^ (row & 7)) * 8;
            gload16(A + (size_t)(m0 + row) * 1024 + k0 + ksrc, &As[chunk * 512]);
            gload16(BT + (size_t)(n0 + row) * 1024 + k0 + ksrc, &Bs[chunk * 512]);
        }
        __syncthreads();
#pragma unroll
        for (int kk = 0; kk < 2; ++kk) {
            f16x8 a[4], b[4];
#pragma unroll
            for (int mi = 0; mi < 4; ++mi) {
                int row = wr + mi * 16 + r;
                int byte = row * 128 + (((kk * 4 + g) ^ (row & 7)) << 4);
                a[mi] = *(const f16x8*)((const char*)As + byte);
            }
#pragma unroll
            for (int ni = 0; ni < 4; ++ni) {
                int row = wc + ni * 16 + r;
                int byte = row * 128 + (((kk * 4 + g) ^ (row & 7)) << 4);
                b[ni] = *(const f16x8*)((const char*)Bs + byte);
            }
#pragma unroll
            for (int mi = 0; mi < 4; ++mi)
#pragma unroll
                for (int ni = 0; ni < 4; ++ni)
                    acc[mi][ni] = __builtin_amdgcn_mfma_f32_16x16x32_f16(
                        a[mi], b[ni], acc[mi][ni], 0, 0, 0);
        }
    }

    // C/D layout: col = lane&15 (r), row = g*4 + reg (validated m89/R4)
    const int colbase = n0 + wc;        // + ni*16 + r ; one head per wave quadrant
    const int region = colbase >> 10;   // 0=q 1=k 2=v (uniform per block: 1024%128==0)

    if (region < 2) {
        const float* sc = region ? k_scale : q_scale;
        const float sc0 = sc[r], sc1 = sc[r + 16], sc2 = sc[r + 32], sc3 = sc[r + 48];
        const float topmul = region ? 1.0f : 8.0f;
        const int pshift = region ? 0 : 128;
#pragma unroll
        for (int mi = 0; mi < 4; ++mi) {
#pragma unroll
            for (int rr = 0; rr < 4; ++rr) {
                int row = m0 + wr + mi * 16 + g * 4 + rr;
                int nn = row & 8191;
                float x0 = acc[mi][0][rr], x1 = acc[mi][1][rr];
                float x2 = acc[mi][2][rr], x3 = acc[mi][3][rr];
                float ss = x0 * x0 + x1 * x1 + x2 * x2 + x3 * x3;
                ss = dppsum16(ss);  // full 64-d row norm (16 r-lanes x 4 ni)
                float inv = topmul / fmaxf(sqrtf(ss), 1e-12f);
                x0 *= inv * sc0; x1 *= inv * sc1; x2 *= inv * sc2; x3 *= inv * sc3;
                int p = nn + pshift;
                float2 t0 = rt2[p * 32 + r];        // d = r       (pair ni0,ni2)
                float2 t1 = rt2[p * 32 + 16 + r];   // d = r + 16  (pair ni1,ni3)
                float o0 = x0 * t0.x - x2 * t0.y, o2 = x2 * t0.x + x0 * t0.y;
                float o1 = x1 * t1.x - x3 * t1.y, o3 = x3 * t1.x + x1 * t1.y;
                size_t base = (size_t)row * 2048 + colbase + r;
                qk[base]      = f2h(o0);
                qk[base + 16] = f2h(o1);
                qk[base + 32] = f2h(o2);
                qk[base + 48] = f2h(o3);
            }
        }
    } else {
        const int h = (colbase & 1023) >> 6;
#pragma unroll
        for (int mi = 0; mi < 4; ++mi)
#pragma unroll
            for (int ni = 0; ni < 4; ++ni) {
                int d = ni * 16 + r;
#pragma unroll
                for (int rr = 0; rr < 4; ++rr) {
                    int row = m0 + wr + mi * 16 + g * 4 + rr;
                    int bi = row >> 13, nn = row & 8191;
                    vt[((size_t)((bi * 16 + h) * 64 + d)) * 8192 + nn] = f2h(acc[mi][ni][rr]);
                }
            }
    }
}

// ---------------- plain MFMA GEMM (GEMM2, validated): C = A @ BT^T ----------------
template <bool C_F32>
__global__ __launch_bounds__(256) void gemm_mfma(const u16* __restrict__ A, int lda,
                                                 const u16* __restrict__ BT, int ldb,
                                                 void* __restrict__ Cp, int ldc,
                                                 int K) {
    __shared__ __align__(16) u16 As[128 * 64];
    __shared__ __align__(16) u16 Bs[128 * 64];
    const int tid = threadIdx.x;
    const int w = tid >> 6, l = tid & 63;
    const int m0 = blockIdx.y * 128, n0 = blockIdx.x * 128;
    const int wr = (w >> 1) * 64, wc = (w & 1) * 64;
    const int r = l & 15, g = l >> 4;

    f32x4 acc[4][4] = {};

    for (int k0 = 0; k0 < K; k0 += 64) {
        __syncthreads();
#pragma unroll
        for (int i = 0; i < 4; ++i) {
            int chunk = i * 4 + w;
            int row = chunk * 8 + (l >> 3);
            int ksrc = ((l & 7) ^ (row & 7)) * 8;
            gload16(A + (size_t)(m0 + row) * lda + k0 + ksrc, &As[chunk * 512]);
            gload16(BT + (size_t)(n0 + row) * ldb + k0 + ksrc, &Bs[chunk * 512]);
        }
        __syncthreads();
#pragma unroll
        for (int kk = 0; kk < 2; ++kk) {
            f16x8 a[4], b[4];
#pragma unroll
            for (int mi = 0; mi < 4; ++mi) {
                int row = wr + mi * 16 + r;
                int byte = row * 128 + (((kk * 4 + g) ^ (row & 7)) << 4);
                a[mi] = *(const f16x8*)((const char*)As + byte);
            }
#pragma unroll
            for (int ni = 0; ni < 4; ++ni) {
                int row = wc + ni * 16 + r;
                int byte = row * 128 + (((kk * 4 + g) ^ (row & 7)) << 4);
                b[ni] = *(const f16x8*)((const char*)Bs + byte);
            }
#pragma unroll
            for (int mi = 0; mi < 4; ++mi)
#pragma unroll
                for (int ni = 0; ni < 4; ++ni)
                    acc[mi][ni] = __builtin_amdgcn_mfma_f32_16x16x32_f16(
                        a[mi], b[ni], acc[mi][ni], 0, 0, 0);
        }
    }

#pragma unroll
    for (int mi = 0; mi < 4; ++mi)
#pragma unroll
        for (int ni = 0; ni < 4; ++ni) {
            int row0 = m0 + wr + mi * 16 + g * 4;
            int col  = n0 + wc + ni * 16 + r;
#pragma unroll
            for (int rr = 0; rr < 4; ++rr) {
                size_t idx = (size_t)(row0 + rr) * ldc + col;
                if (C_F32) ((float*)Cp)[idx] = acc[mi][ni][rr];
                else       ((u16*)Cp)[idx]   = f2h(acc[mi][ni][rr]);
            }
        }
}

// ---------------- fp32-VALU GEMM fallback (proven R2/R4): C = A(f16) @ B(f32) ----------------

DEV int cmap(int c) { return c + ((c >> 5) << 2); }

__global__ __launch_bounds__(256) void gemm_nn_f32(const u16* __restrict__ A, int lda,
                                                   const float* __restrict__ B,
                                                   float* __restrict__ Cp, int ldc,
                                                   int N, int K) {
    __shared__ __align__(16) float As[16][132];
    __shared__ __align__(16) float Bs[16][140];
    const int tid = threadIdx.x;
    const int m0 = blockIdx.y * 128, n0 = blockIdx.x * 128;
    const int tx = tid & 15, ty = tid >> 4;
    const int txm = cmap(tx * 8);

    const int ar = tid >> 1, ac = (tid & 1) * 8;
    const int br = tid >> 4, bc = (tid & 15) * 8;
    const int bcm = cmap(bc);

    float acc[8][8] = {};

    for (int k0 = 0; k0 < K; k0 += 16) {
        __syncthreads();
        {
            uint4 av = *(const uint4*)(A + (size_t)(m0 + ar) * lda + k0 + ac);
            As[ac + 0][ar] = hlo(av.x); As[ac + 1][ar] = hhi(av.x);
            As[ac + 2][ar] = hlo(av.y); As[ac + 3][ar] = hhi(av.y);
            As[ac + 4][ar] = hlo(av.z); As[ac + 5][ar] = hhi(av.z);
            As[ac + 6][ar] = hlo(av.w); As[ac + 7][ar] = hhi(av.w);
        }
        {
            const float* bp = B + (size_t)(k0 + br) * N + n0 + bc;
            float4 b0 = *(const float4*)bp, b1 = *(const float4*)(bp + 4);
            *(float4*)&Bs[br][bcm]     = b0;
            *(float4*)&Bs[br][bcm + 4] = b1;
        }
        __syncthreads();
#pragma unroll
        for (int kk = 0; kk < 16; ++kk) {
            float4 a0 = *(const float4*)&As[kk][ty * 8];
            float4 a1 = *(const float4*)&As[kk][ty * 8 + 4];
            float4 b0 = *(const float4*)&Bs[kk][txm];
            float4 b1 = *(const float4*)&Bs[kk][txm + 4];
            float a[8] = {a0.x, a0.y, a0.z, a0.w, a1.x, a1.y, a1.z, a1.w};
            float b[8] = {b0.x, b0.y, b0.z, b0.w, b1.x, b1.y, b1.z, b1.w};
#pragma unroll
            for (int i = 0; i < 8; ++i)
#pragma unroll
                for (int j = 0; j < 8; ++j) acc[i][j] += a[i] * b[j];
        }
    }

#pragma unroll
    for (int i = 0; i < 8; ++i) {
        size_t row = (size_t)(m0 + ty * 8 + i);
        float* cp = Cp + row * ldc + n0 + tx * 8;
        *(float4*)cp       = make_float4(acc[i][0], acc[i][1], acc[i][2], acc[i][3]);
        *(float4*)(cp + 4) = make_float4(acc[i][4], acc[i][5], acc[i][6], acc[i][7]);
    }
}

// ---------------- MFMA local attention v2: pure-copy staging ----------------
// Q/K arrive pre-roped+normalized (global phases), V pre-transposed.
// 1 block = (bh, win), 4 waves; wave w owns query rows [32w, 32w+32).
// LDS: P per-wave [0,18432) (32x72 f16 rows, 144B); K tile [18432,26624);
//      Vt tile [26624,34816). K/Vt tiles [64 rows][64 k] f16 XOR-swizzled,
//      staged by gload16 with inverse-swizzled source (validated gemm pattern).

#define POFF  0
#define KOFF  18432
#define VOFF  26624

__global__ __launch_bounds__(256, 3) void attn_mfma2(u16* __restrict__ qk,
                                                     const u16* __restrict__ vt) {
    __shared__ __align__(16) char SMB[34816];

    const int win = blockIdx.x, bh = blockIdx.y;
    const int bi = bh >> 4, h = bh & 15;
    const int tid = threadIdx.x;
    const int w = tid >> 6, l = tid & 63;
    const int r = l & 15, g = l >> 4;

    // ---- Q fragments: direct global->reg (rows pre-roped, 128 B fully consumed) ----
    f16x8 aq[2][2];
#pragma unroll
    for (int mi = 0; mi < 2; ++mi)
#pragma unroll
        for (int kk = 0; kk < 2; ++kk)
            aq[mi][kk] = *(const f16x8*)(qk
                + (size_t)(bi * 8192 + win * 128 + w * 32 + mi * 16 + r) * 2048
                + h * 64 + (kk * 4 + g) * 8);

    f32x4 acc_o[2][4] = {};
    float m[2][4], lsum[2][4];
#pragma unroll
    for (int mi = 0; mi < 2; ++mi)
#pragma unroll
        for (int rr = 0; rr < 4; ++rr) { m[mi][rr] = NEGF; lsum[mi][rr] = 0.f; }

    const int cl = (win == 0) ? 2 : 0;
    const int ch = (win == 63) ? 3 : 5;
    const int wlo = w >> 1;
    const int whi = wlo + 4;
    const size_t krow0 = (size_t)(bi * 8192 + (win - 1) * 128);
    const size_t vrow0 = (size_t)((bi * 16 + h) * 64);
    const int    jb0   = (win - 1) * 128;

    for (int c = cl; c <= ch; ++c) {
        __syncthreads();  // previous chunk's LDS reads complete
        // ---- stage K + Vt tiles: 2 segs per wave each, zero VALU transform ----
#pragma unroll
        for (int i = 0; i < 2; ++i) {
            int seg = w + i * 4;                    // 0..7
            int row = seg * 8 + (l >> 3);           // 0..63
            int slot = (l & 7) ^ (row & 7);         // inverse-swizzled source
            gload16(qk + (krow0 + c * 64 + row) * 2048 + 1024 + h * 64 + slot * 8,
                    SMB + KOFF + seg * 1024);
            gload16(vt + (vrow0 + row) * 8192 + jb0 + c * 64 + slot * 8,
                    SMB + VOFF + seg * 1024);
        }
        __syncthreads();  // staging visible (vmcnt drained by barrier)

        if (c < wlo || c > whi) continue;

        // ---- S = Q K^T (swizzled K reads) ----
        f32x4 acc_s[2][4] = {};
#pragma unroll
        for (int kk = 0; kk < 2; ++kk) {
#pragma unroll
            for (int nj = 0; nj < 4; ++nj) {
                int row = nj * 16 + r;
                f16x8 bk = *(const f16x8*)(SMB + KOFF + row * 128
                                           + (((kk * 4 + g) ^ (row & 7)) << 4));
#pragma unroll
                for (int mi = 0; mi < 2; ++mi)
                    acc_s[mi][nj] = __builtin_amdgcn_mfma_f32_16x16x32_f16(
                        aq[mi][kk], bk, acc_s[mi][nj], 0, 0, 0);
            }
        }

        // ---- mask + online softmax (unchanged from validated R6) ----
        float al_[2][4];
#pragma unroll
        for (int mi = 0; mi < 2; ++mi) {
#pragma unroll
            for (int rr = 0; rr < 4; ++rr) {
                const int qiw = w * 32 + mi * 16 + g * 4 + rr;
                float sv[4];
#pragma unroll
                for (int nj = 0; nj < 4; ++nj) {
                    int jp = c * 64 + nj * 16 + r;
                    bool ok = (jp >= qiw) && (jp <= qiw + 256);
                    sv[nj] = ok ? acc_s[mi][nj][rr] : NEGF;
                }
                float cm = fmaxf(fmaxf(sv[0], sv[1]), fmaxf(sv[2], sv[3]));
                cm = dppmax16(cm);
                float mn = fmaxf(m[mi][rr], cm);
                float al = exp2f((m[mi][rr] - mn) * LOG2E);
                float ps = 0.f;
#pragma unroll
                for (int nj = 0; nj < 4; ++nj) {
                    int jp = c * 64 + nj * 16 + r;
                    bool ok = (jp >= qiw) && (jp <= qiw + 256);
                    float p = ok ? exp2f((sv[nj] - mn) * LOG2E) : 0.f;
                    *(u16*)(SMB + POFF + w * 4608 + (mi * 16 + g * 4 + rr) * 144
                            + (nj * 16 + r) * 2) = f2h(p);
                    ps += p;
                }
                ps = dppsum16(ps);
                lsum[mi][rr] = lsum[mi][rr] * al + ps;
                m[mi][rr] = mn;
                al_[mi][rr] = al;
            }
        }
#pragma unroll
        for (int mi = 0; mi < 2; ++mi)
#pragma unroll
            for (int ni = 0; ni < 4; ++ni)
#pragma unroll
                for (int rr = 0; rr < 4; ++rr)
                    acc_o[mi][ni][rr] *= al_[mi][rr];

        // ---- O += P V (P per-wave LDS, Vt swizzled) ----
#pragma unroll
        for (int kkj = 0; kkj < 2; ++kkj) {
            f16x8 pa[2];
#pragma unroll
            for (int mi = 0; mi < 2; ++mi)
                pa[mi] = *(const f16x8*)(SMB + POFF + w * 4608 + (mi * 16 + r) * 144
                                         + (kkj * 4 + g) * 16);
#pragma unroll
            for (int ni = 0; ni < 4; ++ni) {
                int row = ni * 16 + r;
                f16x8 bv = *(const f16x8*)(SMB + VOFF + row * 128
                                           + (((kkj * 4 + g) ^ (row & 7)) << 4));
#pragma unroll
                for (int mi = 0; mi < 2; ++mi)
                    acc_o[mi][ni] = __builtin_amdgcn_mfma_f32_16x16x32_f16(
                        pa[mi], bv, acc_o[mi][ni], 0, 0, 0);
            }
        }
    }

    // ---- epilogue: O/l into the q-slots (fp16, ld 2048) ----
#pragma unroll
    for (int mi = 0; mi < 2; ++mi) {
        float linv[4];
#pragma unroll
        for (int rr = 0; rr < 4; ++rr) linv[rr] = 1.0f / lsum[mi][rr];
#pragma unroll
        for (int ni = 0; ni < 4; ++ni)
#pragma unroll
            for (int rr = 0; rr < 4; ++rr) {
                int q = win * 128 + w * 32 + mi * 16 + g * 4 + rr;
                qk[((size_t)(bi * 8192 + q)) * 2048 + h * 64 + ni * 16 + r]
                    = f2h(acc_o[mi][ni][rr] * linv[rr]);
            }
    }
}

// ---------------- host launcher ----------------

extern "C" void kernel_launch(void* const* d_in, const int* in_sizes, int n_in,
                              void* d_out, int out_size, void* d_ws, size_t ws_size,
                              hipStream_t stream) {
    const float* x       = (const float*)d_in[0];  // [16384, 1024]
    const float* w_qkv   = (const float*)d_in[1];  // [1024, 3072]
    const float* w_out   = (const float*)d_in[2];  // [1024, 1024]
    const float* q_scale = (const float*)d_in[3];  // [64]
    const float* k_scale = (const float*)d_in[4];  // [64]
    float* outp = (float*)d_out;

    // ws layout (total 100,663,296 B -- SAME validated extent as R4-R6):
    //   qk [0, 67,108,864):            16384 rows x 2048 f16 (q|k, roped; O overwrites q)
    //   vt [67,108,864, 100,663,296):  [2][16][64][8192] f16 (V transposed)
    //   woT at 100,663,296 ONLY if ws_size proves it exists.
    u16* qk = (u16*)d_ws;
    u16* vt = (u16*)((char*)d_ws + 67108864);
    const size_t QKV_BYTES = 100663296;
    const size_t WOT_BYTES = 2097152;
    bool ws_has_wot = (ws_size >= QKV_BYTES + WOT_BYTES);
    u16* woT = (u16*)((char*)d_ws + QKV_BYTES);

    // d_out staging (all consumed before GEMM2 writes d_out):
    //   xh  [0, 33,554,432)           16384x1024 fp16
    //   wqT [33,554,432, 39,845,888)   3072x1024 fp16
    //   rt2 [39,845,888, 41,975,808)   8320x32 float2 rope table
    u16*    xh  = (u16*)d_out;
    u16*    wqT = (u16*)((char*)d_out + 33554432);
    float2* rt2 = (float2*)((char*)d_out + 39845888);

    rope_table2<<<dim3(1040), 256, 0, stream>>>(rt2);
    cvt_f32_f16<<<dim3(2048), 256, 0, stream>>>(x, xh, 2097152);
    transpose_cvt<<<dim3(96, 32), 256, 0, stream>>>(w_qkv, wqT, 1024, 3072);
    if (ws_has_wot)
        transpose_cvt<<<dim3(32, 32), 256, 0, stream>>>(w_out, woT, 1024, 1024);

    // GEMM1 + fused norm/scale/rope epilogue -> qk (roped) + vt (transposed)
    gemm_qkv<<<dim3(24, 128), 256, 0, stream>>>(xh, wqT, qk, vt, q_scale, k_scale, rt2);
    // attention (pure-copy staging); O overwrites the q-slots of qk
    attn_mfma2<<<dim3(64, 32), 256, 0, stream>>>(qk, vt);
    // out = O @ w_out
    if (ws_has_wot)
        gemm_mfma<true><<<dim3(8, 128), 256, 0, stream>>>(qk, 2048, woT, 1024, outp, 1024, 1024);
    else
        gemm_nn_f32<<<dim3(8, 128), 256, 0, stream>>>(qk, 2048, w_out, outp, 1024, 1024, 1024);
}